// Round 5
// baseline (899.338 us; speedup 1.0000x reference)
//
#include <hip/hip_runtime.h>

#define NB 16
#define NC 768
#define NT 512
#define KS 384
#define NPX 4096
#define BK 64

typedef __bf16 bfx8 __attribute__((ext_vector_type(8)));
typedef float fx4 __attribute__((ext_vector_type(4)));
typedef unsigned short u16;
typedef unsigned short usv4 __attribute__((ext_vector_type(4)));

__device__ __forceinline__ u16 f2bf(float f) {
  unsigned u = __builtin_bit_cast(unsigned, f);
  u += 0x7FFFu + ((u >> 16) & 1u);
  return (u16)(u >> 16);
}
__device__ __forceinline__ float bf2f(u16 v) {
  return __builtin_bit_cast(float, (unsigned)v << 16);
}

__device__ __forceinline__ void gload16(const u16* g, u16* l) {
  __builtin_amdgcn_global_load_lds(
      (const __attribute__((address_space(1))) unsigned int*)g,
      (__attribute__((address_space(3))) unsigned int*)l, 16, 0, 0);
}

// ---- K1: x -> bf16 xT[b][px][c] (transposed) + xC[b][c][px] (cast) + partial sums ----
__global__ void k_trans_mean(const float* __restrict__ x, u16* __restrict__ xT,
                             u16* __restrict__ xC, float* __restrict__ parts) {
  __shared__ float ld[64][65];
  int p0 = blockIdx.x * 64, c0 = blockIdx.y * 64, b = blockIdx.z;
  int t = threadIdx.x;
  int k = t & 15, ir = t >> 4;
  int jr = k * 4;
#pragma unroll
  for (int s = 0; s < 4; ++s) {
    int i = ir + s * 16;
    float4 v = *(const float4*)&x[(size_t)(b * NC + c0 + i) * NPX + p0 + jr];
    ld[i][jr] = v.x; ld[i][jr + 1] = v.y; ld[i][jr + 2] = v.z; ld[i][jr + 3] = v.w;
    usv4 pk = {f2bf(v.x), f2bf(v.y), f2bf(v.z), f2bf(v.w)};
    *(usv4*)&xC[(size_t)(b * NC + c0 + i) * NPX + p0 + jr] = pk;
  }
  __syncthreads();
#pragma unroll
  for (int s = 0; s < 4; ++s) {
    int j = ir + s * 16;
    usv4 pk = {f2bf(ld[k * 4][j]), f2bf(ld[k * 4 + 1][j]),
               f2bf(ld[k * 4 + 2][j]), f2bf(ld[k * 4 + 3][j])};
    *(usv4*)&xT[(size_t)(b * NPX + p0 + j) * NC + c0 + k * 4] = pk;
  }
  if (t < 64) {
    float s = 0.f;
    for (int j = 0; j < 64; ++j) s += ld[t][j];
    parts[(size_t)(b * NC + c0 + t) * 64 + blockIdx.x] = s;
  }
}

// ---- fused prompt path: silu(temb) -> ss/tp -> p -> hid -> pr -> topk ----
// one block per batch, 1024 threads (16 waves), wave-cooperative dots
__global__ __launch_bounds__(1024, 1) void k_prompt(
    const float* __restrict__ temb, const float* __restrict__ parts,
    const float* __restrict__ W_ts, const float* __restrict__ b_ts,
    const float* __restrict__ W_tp, const float* __restrict__ b_tp,
    const float* __restrict__ W_m1, const float* __restrict__ b_m1,
    const float* __restrict__ W_m2, const float* __restrict__ b_m2,
    float* __restrict__ xmean_g, float* __restrict__ Y1, int* __restrict__ idx) {
  __shared__ float st[512];
  __shared__ float ssl[2304];
  __shared__ float pl[1536];
  __shared__ float hidl[1536];
  __shared__ float prl[768];
  __shared__ float xml[768];
  int b = blockIdx.x, t = threadIdx.x, lane = t & 63, w = t >> 6;

  if (t < 512) { float v = temb[b * 512 + t]; st[t] = v / (1.f + expf(-v)); }
  if (t < 768) {
    const float* pp = parts + (size_t)(b * 768 + t) * 64;
    float s = 0.f;
    for (int j = 0; j < 64; ++j) s += pp[j];
    float xm = s * (1.f / 4096.f);
    xml[t] = xm;
    xmean_g[b * 768 + t] = xm;
  }
  __syncthreads();

  // ss (1536 rows, W_ts) + tp (768 rows, W_tp), len 512
  for (int j = w; j < 2304; j += 16) {
    const float* wr = (j < 1536) ? W_ts + (size_t)j * 512 : W_tp + (size_t)(j - 1536) * 512;
    float4 a0 = *(const float4*)&wr[lane * 8];
    float4 a1 = *(const float4*)&wr[lane * 8 + 4];
    float4 s0 = *(const float4*)&st[lane * 8];
    float4 s1 = *(const float4*)&st[lane * 8 + 4];
    float acc = a0.x * s0.x + a0.y * s0.y + a0.z * s0.z + a0.w * s0.w +
                a1.x * s1.x + a1.y * s1.y + a1.z * s1.z + a1.w * s1.w;
#pragma unroll
    for (int m = 32; m; m >>= 1) acc += __shfl_xor(acc, m);
    if (lane == 0) {
      acc += (j < 1536) ? b_ts[j] : b_tp[j - 1536];
      ssl[j] = acc;
      if (j < 1536) Y1[(size_t)b * 2304 + j] = acc;
    }
  }
  __syncthreads();

  if (t < 768) {
    pl[t] = xml[t] * (1.f + ssl[t]) + ssl[768 + t];
    pl[768 + t] = ssl[1536 + t];
  }
  __syncthreads();

  // hid = silu(W_m1 @ p + b_m1), 1536 rows, len 1536
  for (int j = w; j < 1536; j += 16) {
    const float* wr = W_m1 + (size_t)j * 1536;
    float acc = 0.f;
#pragma unroll
    for (int e = 0; e < 6; ++e) {
      float4 a = *(const float4*)&wr[lane * 24 + e * 4];
      float4 s = *(const float4*)&pl[lane * 24 + e * 4];
      acc += a.x * s.x + a.y * s.y + a.z * s.z + a.w * s.w;
    }
#pragma unroll
    for (int m = 32; m; m >>= 1) acc += __shfl_xor(acc, m);
    if (lane == 0) {
      acc += b_m1[j];
      hidl[j] = acc / (1.f + expf(-acc));
    }
  }
  __syncthreads();

  // pr = W_m2 @ hid + b_m2, 768 rows, len 1536
  for (int j = w; j < 768; j += 16) {
    const float* wr = W_m2 + (size_t)j * 1536;
    float acc = 0.f;
#pragma unroll
    for (int e = 0; e < 6; ++e) {
      float4 a = *(const float4*)&wr[lane * 24 + e * 4];
      float4 s = *(const float4*)&hidl[lane * 24 + e * 4];
      acc += a.x * s.x + a.y * s.y + a.z * s.z + a.w * s.w;
    }
#pragma unroll
    for (int m = 32; m; m >>= 1) acc += __shfl_xor(acc, m);
    if (lane == 0) prl[j] = acc + b_m2[j];
  }
  __syncthreads();

  // topk by rank counting (set-exact)
  if (t < 768) {
    float v = prl[t];
    int r = 0;
    for (int c2 = 0; c2 < 768; ++c2) {
      float v2 = prl[c2];
      r += (v2 > v) || (v2 == v && c2 < t);
    }
    if (r < KS) idx[b * KS + r] = t;
  }
}

// ---- fold scale into gathered rows; shift into bias; sigma for S corrections ----
__global__ void k_fold(const int* __restrict__ idx, const float* __restrict__ Y1,
                       const float* __restrict__ xmean,
                       const float* __restrict__ Wq, const float* __restrict__ bq,
                       const float* __restrict__ Wk, const float* __restrict__ bk,
                       const float* __restrict__ Wv, const float* __restrict__ bv,
                       u16* __restrict__ Aq, u16* __restrict__ Avtmp,
                       float* __restrict__ biasq, float* __restrict__ sig) {
  __shared__ float red[5 * 256];
  int k = blockIdx.x, b = blockIdx.y, t = threadIdx.x;
  int row = idx[b * KS + k];
  const float* yb = Y1 + (size_t)b * 2304;
  u16* aq = Aq + (size_t)b * 768 * NC;
  u16* av = Avtmp + (size_t)b * KS * NC;
  float dq = 0.f, dk = 0.f, dv = 0.f, sq = 0.f, sk = 0.f;
  for (int c = t; c < NC; c += 256) {
    float sc = 1.f + yb[c], sh = yb[768 + c];
    float xm = xmean[b * NC + c];
    float wq = Wq[(size_t)row * NC + c];
    float wk = Wk[(size_t)row * NC + c];
    float wv = Wv[(size_t)row * NC + c];
    aq[(size_t)k * NC + c] = f2bf(wq * sc);
    aq[(size_t)(KS + k) * NC + c] = f2bf(wk * sc);
    av[(size_t)k * NC + c] = f2bf(wv * sc);
    dq += wq * sh; dk += wk * sh; dv += wv * sh;
    sq += wq * sc * xm; sk += wk * sc * xm;
  }
  red[t] = dq; red[256 + t] = dk; red[512 + t] = dv; red[768 + t] = sq; red[1024 + t] = sk;
  __syncthreads();
  for (int s = 128; s; s >>= 1) {
    if (t < s) {
#pragma unroll
      for (int q = 0; q < 5; ++q) red[q * 256 + t] += red[q * 256 + t + s];
    }
    __syncthreads();
  }
  if (t == 0) {
    biasq[b * 1152 + k] = bq[row] + red[0];
    biasq[b * 1152 + KS + k] = bk[row] + red[256];
    biasq[b * 1152 + 2 * KS + k] = bv[row] + red[512];
    sig[b * NC + k] = 4096.f * red[768];
    sig[b * NC + KS + k] = 4096.f * red[1024];
  }
}

// ---- transpose Avtmp[b][384][768] -> AvT[b][768][384] ----
__global__ void k_avt(const u16* __restrict__ Avtmp, u16* __restrict__ AvT) {
  __shared__ u16 tl[64][65];
  int lt = blockIdx.x % 6, ct = blockIdx.x / 6, b = blockIdx.y;
  int l0 = lt * 64, c0 = ct * 64, t = threadIdx.x;
#pragma unroll
  for (int s = 0; s < 16; ++s) {
    int id = t + 256 * s;
    int r = id >> 6, c = id & 63;
    tl[r][c] = Avtmp[(size_t)b * KS * NC + (size_t)(l0 + r) * NC + c0 + c];
  }
  __syncthreads();
#pragma unroll
  for (int s = 0; s < 16; ++s) {
    int id = t + 256 * s;
    int r = id >> 6, c = id & 63;
    AvT[(size_t)b * NC * KS + (size_t)(c0 + r) * KS + l0 + c] = tl[c][r];
  }
}

// ---- gather Wo columns ----
__global__ void k_gather_wo(const int* __restrict__ idx, const float* __restrict__ Wo,
                            u16* __restrict__ WoSel) {
  __shared__ int il[KS];
  int b = blockIdx.y, t = threadIdx.x;
  for (int k = t; k < KS; k += 256) il[k] = idx[b * KS + k];
  __syncthreads();
  int o0 = blockIdx.x * 8;
  for (int oo = 0; oo < 8; ++oo) {
    int o = o0 + oo;
    const float* wr = Wo + (size_t)o * NC;
    u16* dst = WoSel + ((size_t)b * NC + o) * KS;
    for (int k = t; k < KS; k += 256) dst[k] = f2bf(wr[il[k]]);
  }
}

// ---- merge 2 Gram split-K partials (packed lower tiles) -> full symmetric bf16 G ----
__global__ void k_gmerge(const float* __restrict__ Gp, u16* __restrict__ G) {
  __shared__ u16 gl[128][130];
  int tt = blockIdx.x, b = blockIdx.y, t = threadIdx.x;
  int i = 0;
  while ((i + 1) * (i + 2) / 2 <= tt) ++i;
  int j = tt - i * (i + 1) / 2;
  const float* p0 = Gp + ((size_t)(0 * NB + b) * 21 + tt) * 16384;
  const float* p1 = Gp + ((size_t)(1 * NB + b) * 21 + tt) * 16384;
#pragma unroll
  for (int s = 0; s < 16; ++s) {
    int id = t + 256 * s;
    int row = id >> 5, col4 = (id & 31) * 4;
    float4 a = *(const float4*)&p0[row * 128 + col4];
    float4 bb = *(const float4*)&p1[row * 128 + col4];
    usv4 pk = {f2bf(a.x + bb.x), f2bf(a.y + bb.y), f2bf(a.z + bb.z), f2bf(a.w + bb.w)};
    gl[row][col4] = pk[0]; gl[row][col4 + 1] = pk[1];
    gl[row][col4 + 2] = pk[2]; gl[row][col4 + 3] = pk[3];
    *(usv4*)&G[((size_t)b * NC + i * 128 + row) * NC + j * 128 + col4] = pk;
  }
  if (i == j) return;
  __syncthreads();
#pragma unroll
  for (int s = 0; s < 16; ++s) {
    int id = t + 256 * s;
    int row = id >> 5, col4 = (id & 31) * 4;
    usv4 pk = {gl[col4][row], gl[col4 + 1][row], gl[col4 + 2][row], gl[col4 + 3][row]};
    *(usv4*)&G[((size_t)b * NC + j * 128 + row) * NC + i * 128 + col4] = pk;
  }
}

// ---- row softmax of S, write transposed bf16 At[b][l][k] ----
__global__ void k_softmax(const float* __restrict__ S, u16* __restrict__ At) {
  __shared__ float sh[2];
  int kk = blockIdx.x, b = blockIdx.y, t = threadIdx.x;  // 128 threads
  const float* srow = S + ((size_t)b * KS + kk) * KS;
  float v[3];
#pragma unroll
  for (int i = 0; i < 3; ++i) v[i] = srow[t + 128 * i];
  float m = fmaxf(fmaxf(v[0], v[1]), v[2]);
#pragma unroll
  for (int s = 32; s; s >>= 1) m = fmaxf(m, __shfl_xor(m, s));
  if ((t & 63) == 0) sh[t >> 6] = m;
  __syncthreads();
  m = fmaxf(sh[0], sh[1]);
  float e[3];
  float sum = 0.f;
#pragma unroll
  for (int i = 0; i < 3; ++i) { e[i] = expf(v[i] - m); sum += e[i]; }
#pragma unroll
  for (int s = 32; s; s >>= 1) sum += __shfl_xor(sum, s);
  __syncthreads();
  if ((t & 63) == 0) sh[t >> 6] = sum;
  __syncthreads();
  sum = sh[0] + sh[1];
  float inv = 1.f / sum;
#pragma unroll
  for (int i = 0; i < 3; ++i) {
    int l = t + 128 * i;
    At[((size_t)b * KS + l) * KS + kk] = f2bf(e[i] * inv);
  }
}

// ---- bias_fin[b][o] = bo[o] + sum_l R[b][o][l] * betav[b][l] ----
__global__ void k_bias_fin(const u16* __restrict__ R, const float* __restrict__ biasq,
                           const float* __restrict__ bo, float* __restrict__ bias_fin) {
  __shared__ float bvl[KS];
  int b = blockIdx.y, t = threadIdx.x, lane = t & 63, w = t >> 6;
  for (int l = t; l < KS; l += 256) bvl[l] = biasq[b * 1152 + 768 + l];
  __syncthreads();
  int o0 = blockIdx.x * 16;
  for (int oo = w; oo < 16; oo += 4) {
    int o = o0 + oo;
    const u16* rr = R + ((size_t)b * NC + o) * KS;
    float acc = 0.f;
#pragma unroll
    for (int e = 0; e < 6; ++e) {
      int l = lane + 64 * e;
      acc += bf2f(rr[l]) * bvl[l];
    }
#pragma unroll
    for (int m = 32; m; m >>= 1) acc += __shfl_xor(acc, m);
    if (lane == 0) bias_fin[b * NC + o] = acc + bo[o];
  }
}

// ---- GEMM C = A @ Bt^T via global_load_lds staging ----
// EPI 1: S fp32 + rank-1 bias corrections, *scale
// EPI 2: bf16 C[b][row][col]      EPI 3: fp32 C + bias[b][row]
// EPI 5: Gram partial, packed lower-tri tiles, split-K=2
template <int EPI>
__global__ __launch_bounds__(256, 4) void gemm_bt(
    const u16* __restrict__ A, const u16* __restrict__ Bt, size_t sA, size_t sB,
    int ldA, int ldB, int K, const float* __restrict__ bias, int bstride,
    float* __restrict__ outF, u16* __restrict__ outU, int ldC, size_t sC,
    const float* __restrict__ sigp, const float* __restrict__ bqp, float scale) {
  __shared__ u16 As[128 * BK];
  __shared__ u16 Bs[128 * BK];
  int b, m0, n0, kbeg = 0, kend = K, tt = 0, gpart = 0;
  if constexpr (EPI == 5) {
    tt = blockIdx.x;
    int ii = 0;
    while ((ii + 1) * (ii + 2) / 2 <= tt) ++ii;
    int jj = tt - ii * (ii + 1) / 2;
    m0 = ii * 128; n0 = jj * 128;
    b = blockIdx.z >> 1; gpart = blockIdx.z & 1;
    kbeg = gpart * 2048; kend = kbeg + 2048;
  } else {
    b = blockIdx.z; m0 = blockIdx.y * 128; n0 = blockIdx.x * 128;
  }
  const u16* Ab = A + (size_t)b * sA;
  const u16* Bb = Bt + (size_t)b * sB;
  int t = threadIdx.x, lane = t & 63, w = t >> 6;
  int wm = (w >> 1) * 64, wn = (w & 1) * 64;
  int r16 = lane & 15, g = lane >> 4;

  int srow = w * 32 + (lane >> 3);
  int scol = (lane & 7) * 8;
  const u16* Ag = Ab + (size_t)(m0 + srow) * ldA + kbeg + scol;
  const u16* Bg = Bb + (size_t)(n0 + srow) * ldB + kbeg + scol;
  u16* Asl = &As[(w * 32) * BK];
  u16* Bsl = &Bs[(w * 32) * BK];

  fx4 acc[4][4] = {};

  for (int k0 = kbeg; k0 < kend; k0 += BK) {
#pragma unroll
    for (int s = 0; s < 4; ++s) gload16(Ag + (size_t)s * 8 * ldA, Asl + s * 8 * BK);
#pragma unroll
    for (int s = 0; s < 4; ++s) gload16(Bg + (size_t)s * 8 * ldB, Bsl + s * 8 * BK);
    Ag += BK; Bg += BK;
    __syncthreads();
#pragma unroll
    for (int kk = 0; kk < 2; ++kk) {
      bfx8 af[4], bfr[4];
#pragma unroll
      for (int i = 0; i < 4; ++i) {
        af[i] = *(const bfx8*)&As[(wm + i * 16 + r16) * BK + kk * 32 + g * 8];
        bfr[i] = *(const bfx8*)&Bs[(wn + i * 16 + r16) * BK + kk * 32 + g * 8];
      }
#pragma unroll
      for (int i = 0; i < 4; ++i)
#pragma unroll
        for (int j = 0; j < 4; ++j)
          acc[i][j] = __builtin_amdgcn_mfma_f32_16x16x32_bf16(af[i], bfr[j], acc[i][j], 0, 0, 0);
    }
    __syncthreads();
  }

#pragma unroll
  for (int i = 0; i < 4; ++i) {
#pragma unroll
    for (int j = 0; j < 4; ++j) {
      int row = wm + i * 16 + g * 4;   // tile-local
      int col = wn + j * 16 + r16;     // tile-local
      fx4 v = acc[i][j];
      if constexpr (EPI == 1) {        // S with exact bias corrections
        int gc = n0 + col;
        float bk_ = bqp[b * 1152 + 384 + gc];
        float sk_ = sigp[b * NC + 384 + gc];
#pragma unroll
        for (int r = 0; r < 4; ++r) {
          int gr = m0 + row + r;
          float bq_ = bqp[b * 1152 + gr];
          float sq_ = sigp[b * NC + gr];
          float val = (v[r] + bq_ * sk_ + bk_ * sq_ + 4096.f * bq_ * bk_) * scale;
          outF[(size_t)b * sC + (size_t)gr * ldC + gc] = val;
        }
      } else if constexpr (EPI == 2) { // bf16 C
#pragma unroll
        for (int r = 0; r < 4; ++r)
          outU[(size_t)b * sC + (size_t)(m0 + row + r) * ldC + (n0 + col)] = f2bf(v[r]);
      } else if constexpr (EPI == 3) { // fp32 + per-batch bias
#pragma unroll
        for (int r = 0; r < 4; ++r)
          outF[(size_t)b * sC + (size_t)(m0 + row + r) * ldC + (n0 + col)] =
              v[r] + bias[b * bstride + m0 + row + r];
      } else {                         // EPI 5: Gram partial, packed tile
        float* o = outF + ((size_t)(gpart * NB + b) * 21 + tt) * 16384;
#pragma unroll
        for (int r = 0; r < 4; ++r) o[(row + r) * 128 + col] = v[r];
      }
    }
  }
}

__global__ void k_sentinel(float* out, int n) {
  int id = blockIdx.x * 256 + threadIdx.x;
  if (id < n) out[id] = 12345.0f;
}

extern "C" void kernel_launch(void* const* d_in, const int* in_sizes, int n_in,
                              void* d_out, int out_size, void* d_ws, size_t ws_size,
                              hipStream_t stream) {
  const float* x    = (const float*)d_in[0];
  const float* temb = (const float*)d_in[1];
  const float* W_ts = (const float*)d_in[2];
  const float* b_ts = (const float*)d_in[3];
  const float* W_tp = (const float*)d_in[4];
  const float* b_tp = (const float*)d_in[5];
  const float* W_m1 = (const float*)d_in[6];
  const float* b_m1 = (const float*)d_in[7];
  const float* W_m2 = (const float*)d_in[8];
  const float* b_m2 = (const float*)d_in[9];
  const float* Wq = (const float*)d_in[10];
  const float* bq = (const float*)d_in[11];
  const float* Wk = (const float*)d_in[12];
  const float* bk = (const float*)d_in[13];
  const float* Wv = (const float*)d_in[14];
  const float* bv = (const float*)d_in[15];
  const float* Wo = (const float*)d_in[16];
  const float* bo = (const float*)d_in[17];
  float* out = (float*)d_out;

  char* base = (char*)d_ws;
  size_t off = 0;
  auto alloc = [&](size_t bytes) -> char* {
    char* pp = base + off;
    off += (bytes + 255) & ~(size_t)255;
    return pp;
  };
  u16* xT   = (u16*)alloc((size_t)NB * NPX * NC * 2);    // 100.7 MB, live to end
  u16* xC   = (u16*)alloc((size_t)NB * NC * NPX * 2);    // 100.7 MB; G/T/S/At/R/W_eff overlay after G-gemm
  u16* Aq   = (u16*)alloc((size_t)NB * 768 * NC * 2);    // 18.9 MB (q,k rows)
  u16* AvT  = (u16*)alloc((size_t)NB * NC * KS * 2);     // 9.4 MB
  u16* WoS  = (u16*)alloc((size_t)NB * NC * KS * 2);     // 9.4 MB
  float* Gp = (float*)alloc((size_t)2 * NB * 21 * 16384 * 4);  // 44.0 MB; hosts Avtmp early
  float* parts  = (float*)alloc((size_t)NB * NC * 64 * 4);
  float* xmean  = (float*)alloc((size_t)NB * NC * 4);
  float* Y1     = (float*)alloc((size_t)NB * 2304 * 4);
  float* pr     = (float*)alloc((size_t)NB * NC * 4);
  int*   idx    = (int*)alloc((size_t)NB * KS * 4);
  float* biasq  = (float*)alloc((size_t)NB * 1152 * 4);
  float* sig    = (float*)alloc((size_t)NB * NC * 4);
  float* bias_fin = (float*)alloc((size_t)NB * NC * 4);

  if (off > ws_size) {
    k_sentinel<<<(out_size + 255) / 256, 256, 0, stream>>>(out, out_size);
    return;
  }

  // overlays
  u16* Avtmp = (u16*)Gp;                                // 9.4 MB, fold -> avt, dead before G-gemm
  u16* G   = (u16*)xC;                                  // 18.9 MB, after G-gemm frees xC
  u16* T   = (u16*)((char*)xC + 20u * 1024 * 1024);     // 9.4 MB
  float* S = (float*)((char*)xC + 32u * 1024 * 1024);   // 9.4 MB
  u16* At  = (u16*)((char*)xC + 44u * 1024 * 1024);     // 4.7 MB
  u16* R   = (u16*)((char*)xC + 52u * 1024 * 1024);     // 9.4 MB
  u16* Wf  = (u16*)((char*)xC + 64u * 1024 * 1024);     // 18.9 MB

  k_trans_mean<<<dim3(64, 12, NB), 256, 0, stream>>>(x, xT, xC, parts);
  k_prompt<<<NB, 1024, 0, stream>>>(temb, parts, W_ts, b_ts, W_tp, b_tp,
                                    W_m1, b_m1, W_m2, b_m2, xmean, Y1, idx);
  k_fold<<<dim3(KS, NB), 256, 0, stream>>>(idx, Y1, xmean, Wq, bq, Wk, bk, Wv, bv,
                                           Aq, Avtmp, biasq, sig);
  k_avt<<<dim3(72, NB), 256, 0, stream>>>(Avtmp, AvT);
  k_gather_wo<<<dim3(96, NB), 256, 0, stream>>>(idx, Wo, WoS);

  // G = xC @ xC^T (symmetric, lower tiles, split-K=2, packed fp32 partials)
  gemm_bt<5><<<dim3(21, 1, NB * 2), 256, 0, stream>>>(
      xC, xC, (size_t)NC * NPX, (size_t)NC * NPX, NPX, NPX, NPX,
      nullptr, 0, Gp, nullptr, 0, 0, nullptr, nullptr, 0.f);
  k_gmerge<<<dim3(21, NB), 256, 0, stream>>>(Gp, G);
  // T = Ak @ G -> bf16 [b][384][768]
  gemm_bt<2><<<dim3(6, 3, NB), 256, 0, stream>>>(
      Aq + (size_t)KS * NC, G, (size_t)768 * NC, (size_t)NC * NC, NC, NC, NC,
      nullptr, 0, nullptr, T, NC, (size_t)KS * NC, nullptr, nullptr, 0.f);
  // S = (Aq @ T^T + rank-1 bias corrections) * scale -> fp32 [b][384][384]
  gemm_bt<1><<<dim3(3, 3, NB), 256, 0, stream>>>(
      Aq, T, (size_t)768 * NC, (size_t)KS * NC, NC, NC, NC,
      nullptr, 0, S, nullptr, KS, (size_t)KS * KS, sig, biasq, 0.05103103630798287f);
  k_softmax<<<dim3(KS, NB), 128, 0, stream>>>(S, At);
  // R = WoS @ attn (Bt = At = attn^T) -> bf16 [b][768][384]
  gemm_bt<2><<<dim3(3, 6, NB), 256, 0, stream>>>(
      WoS, At, (size_t)NC * KS, (size_t)KS * KS, KS, KS, KS,
      nullptr, 0, nullptr, R, KS, (size_t)NC * KS, nullptr, nullptr, 0.f);
  k_bias_fin<<<dim3(48, NB), 256, 0, stream>>>(R, biasq, bo, bias_fin);
  // W_eff = R @ AvT^T -> bf16 [b][768][768]
  gemm_bt<2><<<dim3(6, 6, NB), 256, 0, stream>>>(
      R, AvT, (size_t)NC * KS, (size_t)NC * KS, KS, KS, KS,
      nullptr, 0, nullptr, Wf, NC, (size_t)NC * NC, nullptr, nullptr, 0.f);
  // out = W_eff @ xT^T + bias_fin -> fp32 [b][768][4096]
  gemm_bt<3><<<dim3(32, 6, NB), 256, 0, stream>>>(
      Wf, xT, (size_t)NC * NC, (size_t)NPX * NC, NC, NC, NC,
      bias_fin, NC, out, nullptr, NPX, (size_t)NC * NPX, nullptr, nullptr, 0.f);
}

// Round 6
// 697.604 us; speedup vs baseline: 1.2892x; 1.2892x over previous
//
#include <hip/hip_runtime.h>

#define NB 16
#define NC 768
#define NT 512
#define KS 384
#define NPX 4096
#define BK 64

typedef __bf16 bfx8 __attribute__((ext_vector_type(8)));
typedef float fx4 __attribute__((ext_vector_type(4)));
typedef unsigned short u16;
typedef unsigned short usv4 __attribute__((ext_vector_type(4)));

__device__ __forceinline__ u16 f2bf(float f) {
  unsigned u = __builtin_bit_cast(unsigned, f);
  u += 0x7FFFu + ((u >> 16) & 1u);
  return (u16)(u >> 16);
}
__device__ __forceinline__ float bf2f(u16 v) {
  return __builtin_bit_cast(float, (unsigned)v << 16);
}

__device__ __forceinline__ void gload16(const u16* g, u16* l) {
  __builtin_amdgcn_global_load_lds(
      (const __attribute__((address_space(1))) unsigned int*)g,
      (__attribute__((address_space(3))) unsigned int*)l, 16, 0, 0);
}

// ---- K1: x -> bf16 xT[b][px][c] (transposed) + xC[b][c][px] (cast) + partial sums ----
__global__ void k_trans_mean(const float* __restrict__ x, u16* __restrict__ xT,
                             u16* __restrict__ xC, float* __restrict__ parts) {
  __shared__ float ld[64][65];
  int p0 = blockIdx.x * 64, c0 = blockIdx.y * 64, b = blockIdx.z;
  int t = threadIdx.x;
  int k = t & 15, ir = t >> 4;
  int jr = k * 4;
#pragma unroll
  for (int s = 0; s < 4; ++s) {
    int i = ir + s * 16;
    float4 v = *(const float4*)&x[(size_t)(b * NC + c0 + i) * NPX + p0 + jr];
    ld[i][jr] = v.x; ld[i][jr + 1] = v.y; ld[i][jr + 2] = v.z; ld[i][jr + 3] = v.w;
    usv4 pk = {f2bf(v.x), f2bf(v.y), f2bf(v.z), f2bf(v.w)};
    *(usv4*)&xC[(size_t)(b * NC + c0 + i) * NPX + p0 + jr] = pk;
  }
  __syncthreads();
#pragma unroll
  for (int s = 0; s < 4; ++s) {
    int j = ir + s * 16;
    usv4 pk = {f2bf(ld[k * 4][j]), f2bf(ld[k * 4 + 1][j]),
               f2bf(ld[k * 4 + 2][j]), f2bf(ld[k * 4 + 3][j])};
    *(usv4*)&xT[(size_t)(b * NPX + p0 + j) * NC + c0 + k * 4] = pk;
  }
  if (t < 64) {
    float s = 0.f;
    for (int j = 0; j < 64; ++j) s += ld[t][j];
    parts[(size_t)(b * NC + c0 + t) * 64 + blockIdx.x] = s;
  }
}

// ---- fused: xmean finalize + silu(temb) ----
__global__ void k_misc(const float* __restrict__ parts, float* __restrict__ xmean,
                       const float* __restrict__ temb, float* __restrict__ st) {
  int id = blockIdx.x * 256 + threadIdx.x;
  if (id < NB * NT) { float v = temb[id]; st[id] = v / (1.f + expf(-v)); }
  if (id < NB * NC) {
    float s = 0.f;
    for (int j = 0; j < 64; ++j) s += parts[(size_t)id * 64 + j];
    xmean[id] = s * (1.f / 4096.f);
  }
}

// ---- small batched MLP: wide launch, weights spread across blocks ----
__global__ void k_mlp8(const float* __restrict__ W, const float* __restrict__ bias,
                       const float* __restrict__ X, float* __restrict__ Y,
                       int len, int nj, int ostride, int obase, int dosilu) {
  __shared__ float Xs[8 * 1537];
  int t = threadIdx.x, lane = t & 63, w = t >> 6;
  int b0 = blockIdx.y * 8;
  int ldx = len + 1;
  for (int id = t; id < 8 * len; id += 256) {
    int bb = id / len, s = id - bb * len;
    Xs[bb * ldx + s] = X[(size_t)(b0 + bb) * len + s];
  }
  __syncthreads();
  for (int i = 0; i < 4; ++i) {
    int j = blockIdx.x * 16 + i * 4 + w;
    if (j < nj) {
      float acc[8] = {0, 0, 0, 0, 0, 0, 0, 0};
      for (int s = lane; s < len; s += 64) {
        float wv = W[(size_t)j * len + s];
#pragma unroll
        for (int bb = 0; bb < 8; ++bb) acc[bb] += wv * Xs[bb * ldx + s];
      }
#pragma unroll
      for (int bb = 0; bb < 8; ++bb) {
        float r = acc[bb];
#pragma unroll
        for (int m = 32; m; m >>= 1) r += __shfl_xor(r, m);
        if (lane == 0) {
          r += bias[j];
          if (dosilu) r = r / (1.f + expf(-r));
          Y[(size_t)(b0 + bb) * ostride + obase + j] = r;
        }
      }
    }
  }
}

// ---- p = [gap, tp]; gap = xmean*(1+scale)+shift ----
__global__ void k_assemble_p(const float* __restrict__ Y1, const float* __restrict__ xmean,
                             float* __restrict__ p) {
  int id = blockIdx.x * 256 + threadIdx.x;
  if (id >= NB * NC) return;
  int b = id / NC, c = id - b * NC;
  const float* yb = Y1 + (size_t)b * 2304;
  p[(size_t)b * 1536 + c] = xmean[id] * (1.f + yb[c]) + yb[768 + c];
  p[(size_t)b * 1536 + 768 + c] = yb[1536 + c];
}

// ---- top-k by rank counting ----
__global__ void k_topk(const float* __restrict__ prompt, int* __restrict__ idx) {
  __shared__ float pr[NC];
  int b = blockIdx.x, t = threadIdx.x;
  for (int c = t; c < NC; c += 256) pr[c] = prompt[(size_t)b * NC + c];
  __syncthreads();
  for (int c = t; c < NC; c += 256) {
    float v = pr[c];
    int r = 0;
    for (int c2 = 0; c2 < NC; ++c2) {
      float v2 = pr[c2];
      r += (v2 > v) || (v2 == v && c2 < c);
    }
    if (r < KS) idx[b * KS + r] = c;
  }
}

// ---- fold scale into gathered rows; shift into bias; sigma for S corrections ----
__global__ void k_fold(const int* __restrict__ idx, const float* __restrict__ Y1,
                       const float* __restrict__ xmean,
                       const float* __restrict__ Wq, const float* __restrict__ bq,
                       const float* __restrict__ Wk, const float* __restrict__ bk,
                       const float* __restrict__ Wv, const float* __restrict__ bv,
                       u16* __restrict__ Aq, u16* __restrict__ Avtmp,
                       float* __restrict__ biasq, float* __restrict__ sig) {
  __shared__ float red[5 * 256];
  int k = blockIdx.x, b = blockIdx.y, t = threadIdx.x;
  int row = idx[b * KS + k];
  const float* yb = Y1 + (size_t)b * 2304;
  u16* aq = Aq + (size_t)b * 768 * NC;
  u16* av = Avtmp + (size_t)b * KS * NC;
  float dq = 0.f, dk = 0.f, dv = 0.f, sq = 0.f, sk = 0.f;
  for (int c = t; c < NC; c += 256) {
    float sc = 1.f + yb[c], sh = yb[768 + c];
    float xm = xmean[b * NC + c];
    float wq = Wq[(size_t)row * NC + c];
    float wk = Wk[(size_t)row * NC + c];
    float wv = Wv[(size_t)row * NC + c];
    aq[(size_t)k * NC + c] = f2bf(wq * sc);
    aq[(size_t)(KS + k) * NC + c] = f2bf(wk * sc);
    av[(size_t)k * NC + c] = f2bf(wv * sc);
    dq += wq * sh; dk += wk * sh; dv += wv * sh;
    sq += wq * sc * xm; sk += wk * sc * xm;
  }
  red[t] = dq; red[256 + t] = dk; red[512 + t] = dv; red[768 + t] = sq; red[1024 + t] = sk;
  __syncthreads();
  for (int s = 128; s; s >>= 1) {
    if (t < s) {
#pragma unroll
      for (int q = 0; q < 5; ++q) red[q * 256 + t] += red[q * 256 + t + s];
    }
    __syncthreads();
  }
  if (t == 0) {
    biasq[b * 1152 + k] = bq[row] + red[0];
    biasq[b * 1152 + KS + k] = bk[row] + red[256];
    biasq[b * 1152 + 2 * KS + k] = bv[row] + red[512];
    sig[b * NC + k] = 4096.f * red[768];
    sig[b * NC + KS + k] = 4096.f * red[1024];
  }
}

// ---- transpose Avtmp[b][384][768] -> AvT[b][768][384] ----
__global__ void k_avt(const u16* __restrict__ Avtmp, u16* __restrict__ AvT) {
  __shared__ u16 tl[64][65];
  int lt = blockIdx.x % 6, ct = blockIdx.x / 6, b = blockIdx.y;
  int l0 = lt * 64, c0 = ct * 64, t = threadIdx.x;
#pragma unroll
  for (int s = 0; s < 16; ++s) {
    int id = t + 256 * s;
    int r = id >> 6, c = id & 63;
    tl[r][c] = Avtmp[(size_t)b * KS * NC + (size_t)(l0 + r) * NC + c0 + c];
  }
  __syncthreads();
#pragma unroll
  for (int s = 0; s < 16; ++s) {
    int id = t + 256 * s;
    int r = id >> 6, c = id & 63;
    AvT[(size_t)b * NC * KS + (size_t)(c0 + r) * KS + l0 + c] = tl[c][r];
  }
}

// ---- gather Wo columns ----
__global__ void k_gather_wo(const int* __restrict__ idx, const float* __restrict__ Wo,
                            u16* __restrict__ WoSel) {
  __shared__ int il[KS];
  int b = blockIdx.y, t = threadIdx.x;
  for (int k = t; k < KS; k += 256) il[k] = idx[b * KS + k];
  __syncthreads();
  int o0 = blockIdx.x * 8;
  for (int oo = 0; oo < 8; ++oo) {
    int o = o0 + oo;
    const float* wr = Wo + (size_t)o * NC;
    u16* dst = WoSel + ((size_t)b * NC + o) * KS;
    for (int k = t; k < KS; k += 256) dst[k] = f2bf(wr[il[k]]);
  }
}

// ---- merge 2 Gram split-K partials (packed lower tiles) -> full symmetric bf16 G ----
__global__ void k_gmerge(const float* __restrict__ Gp, u16* __restrict__ G) {
  __shared__ u16 gl[128][130];
  int tt = blockIdx.x, b = blockIdx.y, t = threadIdx.x;
  int i = 0;
  while ((i + 1) * (i + 2) / 2 <= tt) ++i;
  int j = tt - i * (i + 1) / 2;
  const float* p0 = Gp + ((size_t)(0 * NB + b) * 21 + tt) * 16384;
  const float* p1 = Gp + ((size_t)(1 * NB + b) * 21 + tt) * 16384;
#pragma unroll
  for (int s = 0; s < 16; ++s) {
    int id = t + 256 * s;
    int row = id >> 5, col4 = (id & 31) * 4;
    float4 a = *(const float4*)&p0[row * 128 + col4];
    float4 bb = *(const float4*)&p1[row * 128 + col4];
    usv4 pk = {f2bf(a.x + bb.x), f2bf(a.y + bb.y), f2bf(a.z + bb.z), f2bf(a.w + bb.w)};
    gl[row][col4] = pk[0]; gl[row][col4 + 1] = pk[1];
    gl[row][col4 + 2] = pk[2]; gl[row][col4 + 3] = pk[3];
    *(usv4*)&G[((size_t)b * NC + i * 128 + row) * NC + j * 128 + col4] = pk;
  }
  if (i == j) return;
  __syncthreads();
#pragma unroll
  for (int s = 0; s < 16; ++s) {
    int id = t + 256 * s;
    int row = id >> 5, col4 = (id & 31) * 4;
    usv4 pk = {gl[col4][row], gl[col4 + 1][row], gl[col4 + 2][row], gl[col4 + 3][row]};
    *(usv4*)&G[((size_t)b * NC + j * 128 + row) * NC + i * 128 + col4] = pk;
  }
}

// ---- row softmax of S, write transposed bf16 At[b][l][k] ----
__global__ void k_softmax(const float* __restrict__ S, u16* __restrict__ At) {
  __shared__ float sh[2];
  int kk = blockIdx.x, b = blockIdx.y, t = threadIdx.x;  // 128 threads
  const float* srow = S + ((size_t)b * KS + kk) * KS;
  float v[3];
#pragma unroll
  for (int i = 0; i < 3; ++i) v[i] = srow[t + 128 * i];
  float m = fmaxf(fmaxf(v[0], v[1]), v[2]);
#pragma unroll
  for (int s = 32; s; s >>= 1) m = fmaxf(m, __shfl_xor(m, s));
  if ((t & 63) == 0) sh[t >> 6] = m;
  __syncthreads();
  m = fmaxf(sh[0], sh[1]);
  float e[3];
  float sum = 0.f;
#pragma unroll
  for (int i = 0; i < 3; ++i) { e[i] = expf(v[i] - m); sum += e[i]; }
#pragma unroll
  for (int s = 32; s; s >>= 1) sum += __shfl_xor(sum, s);
  __syncthreads();
  if ((t & 63) == 0) sh[t >> 6] = sum;
  __syncthreads();
  sum = sh[0] + sh[1];
  float inv = 1.f / sum;
#pragma unroll
  for (int i = 0; i < 3; ++i) {
    int l = t + 128 * i;
    At[((size_t)b * KS + l) * KS + kk] = f2bf(e[i] * inv);
  }
}

// ---- bias_fin[b][o] = bo[o] + sum_l R[b][o][l] * betav[b][l] ----
__global__ void k_bias_fin(const u16* __restrict__ R, const float* __restrict__ biasq,
                           const float* __restrict__ bo, float* __restrict__ bias_fin) {
  __shared__ float bvl[KS];
  int b = blockIdx.y, t = threadIdx.x, lane = t & 63, w = t >> 6;
  for (int l = t; l < KS; l += 256) bvl[l] = biasq[b * 1152 + 768 + l];
  __syncthreads();
  int o0 = blockIdx.x * 16;
  for (int oo = w; oo < 16; oo += 4) {
    int o = o0 + oo;
    const u16* rr = R + ((size_t)b * NC + o) * KS;
    float acc = 0.f;
#pragma unroll
    for (int e = 0; e < 6; ++e) {
      int l = lane + 64 * e;
      acc += bf2f(rr[l]) * bvl[l];
    }
#pragma unroll
    for (int m = 32; m; m >>= 1) acc += __shfl_xor(acc, m);
    if (lane == 0) bias_fin[b * NC + o] = acc + bo[o];
  }
}

// ---- GEMM C = A @ Bt^T via global_load_lds staging ----
// EPI 1: S fp32 + rank-1 bias corrections, *scale
// EPI 2: bf16 C[b][row][col]      EPI 3: fp32 C + bias[b][row]
// EPI 5: Gram partial, packed lower-tri tiles, split-K=2
template <int EPI>
__global__ __launch_bounds__(256, 4) void gemm_bt(
    const u16* __restrict__ A, const u16* __restrict__ Bt, size_t sA, size_t sB,
    int ldA, int ldB, int K, const float* __restrict__ bias, int bstride,
    float* __restrict__ outF, u16* __restrict__ outU, int ldC, size_t sC,
    const float* __restrict__ sigp, const float* __restrict__ bqp, float scale) {
  __shared__ u16 As[128 * BK];
  __shared__ u16 Bs[128 * BK];
  int b, m0, n0, kbeg = 0, kend = K, tt = 0, gpart = 0;
  if constexpr (EPI == 5) {
    tt = blockIdx.x;
    int ii = 0;
    while ((ii + 1) * (ii + 2) / 2 <= tt) ++ii;
    int jj = tt - ii * (ii + 1) / 2;
    m0 = ii * 128; n0 = jj * 128;
    b = blockIdx.z >> 1; gpart = blockIdx.z & 1;
    kbeg = gpart * 2048; kend = kbeg + 2048;
  } else {
    b = blockIdx.z; m0 = blockIdx.y * 128; n0 = blockIdx.x * 128;
  }
  const u16* Ab = A + (size_t)b * sA;
  const u16* Bb = Bt + (size_t)b * sB;
  int t = threadIdx.x, lane = t & 63, w = t >> 6;
  int wm = (w >> 1) * 64, wn = (w & 1) * 64;
  int r16 = lane & 15, g = lane >> 4;

  int srow = w * 32 + (lane >> 3);
  int scol = (lane & 7) * 8;
  const u16* Ag = Ab + (size_t)(m0 + srow) * ldA + kbeg + scol;
  const u16* Bg = Bb + (size_t)(n0 + srow) * ldB + kbeg + scol;
  u16* Asl = &As[(w * 32) * BK];
  u16* Bsl = &Bs[(w * 32) * BK];

  fx4 acc[4][4] = {};

  for (int k0 = kbeg; k0 < kend; k0 += BK) {
#pragma unroll
    for (int s = 0; s < 4; ++s) gload16(Ag + (size_t)s * 8 * ldA, Asl + s * 8 * BK);
#pragma unroll
    for (int s = 0; s < 4; ++s) gload16(Bg + (size_t)s * 8 * ldB, Bsl + s * 8 * BK);
    Ag += BK; Bg += BK;
    __syncthreads();
#pragma unroll
    for (int kk = 0; kk < 2; ++kk) {
      bfx8 af[4], bfr[4];
#pragma unroll
      for (int i = 0; i < 4; ++i) {
        af[i] = *(const bfx8*)&As[(wm + i * 16 + r16) * BK + kk * 32 + g * 8];
        bfr[i] = *(const bfx8*)&Bs[(wn + i * 16 + r16) * BK + kk * 32 + g * 8];
      }
#pragma unroll
      for (int i = 0; i < 4; ++i)
#pragma unroll
        for (int j = 0; j < 4; ++j)
          acc[i][j] = __builtin_amdgcn_mfma_f32_16x16x32_bf16(af[i], bfr[j], acc[i][j], 0, 0, 0);
    }
    __syncthreads();
  }

#pragma unroll
  for (int i = 0; i < 4; ++i) {
#pragma unroll
    for (int j = 0; j < 4; ++j) {
      int row = wm + i * 16 + g * 4;   // tile-local
      int col = wn + j * 16 + r16;     // tile-local
      fx4 v = acc[i][j];
      if constexpr (EPI == 1) {        // S with exact bias corrections
        int gc = n0 + col;
        float bk_ = bqp[b * 1152 + 384 + gc];
        float sk_ = sigp[b * NC + 384 + gc];
#pragma unroll
        for (int r = 0; r < 4; ++r) {
          int gr = m0 + row + r;
          float bq_ = bqp[b * 1152 + gr];
          float sq_ = sigp[b * NC + gr];
          float val = (v[r] + bq_ * sk_ + bk_ * sq_ + 4096.f * bq_ * bk_) * scale;
          outF[(size_t)b * sC + (size_t)gr * ldC + gc] = val;
        }
      } else if constexpr (EPI == 2) { // bf16 C
#pragma unroll
        for (int r = 0; r < 4; ++r)
          outU[(size_t)b * sC + (size_t)(m0 + row + r) * ldC + (n0 + col)] = f2bf(v[r]);
      } else if constexpr (EPI == 3) { // fp32 + per-batch bias
#pragma unroll
        for (int r = 0; r < 4; ++r)
          outF[(size_t)b * sC + (size_t)(m0 + row + r) * ldC + (n0 + col)] =
              v[r] + bias[b * bstride + m0 + row + r];
      } else {                         // EPI 5: Gram partial, packed tile
        float* o = outF + ((size_t)(gpart * NB + b) * 21 + tt) * 16384;
#pragma unroll
        for (int r = 0; r < 4; ++r) o[(row + r) * 128 + col] = v[r];
      }
    }
  }
}

__global__ void k_sentinel(float* out, int n) {
  int id = blockIdx.x * 256 + threadIdx.x;
  if (id < n) out[id] = 12345.0f;
}

extern "C" void kernel_launch(void* const* d_in, const int* in_sizes, int n_in,
                              void* d_out, int out_size, void* d_ws, size_t ws_size,
                              hipStream_t stream) {
  const float* x    = (const float*)d_in[0];
  const float* temb = (const float*)d_in[1];
  const float* W_ts = (const float*)d_in[2];
  const float* b_ts = (const float*)d_in[3];
  const float* W_tp = (const float*)d_in[4];
  const float* b_tp = (const float*)d_in[5];
  const float* W_m1 = (const float*)d_in[6];
  const float* b_m1 = (const float*)d_in[7];
  const float* W_m2 = (const float*)d_in[8];
  const float* b_m2 = (const float*)d_in[9];
  const float* Wq = (const float*)d_in[10];
  const float* bq = (const float*)d_in[11];
  const float* Wk = (const float*)d_in[12];
  const float* bk = (const float*)d_in[13];
  const float* Wv = (const float*)d_in[14];
  const float* bv = (const float*)d_in[15];
  const float* Wo = (const float*)d_in[16];
  const float* bo = (const float*)d_in[17];
  float* out = (float*)d_out;

  char* base = (char*)d_ws;
  size_t off = 0;
  auto alloc = [&](size_t bytes) -> char* {
    char* pp = base + off;
    off += (bytes + 255) & ~(size_t)255;
    return pp;
  };
  u16* xT   = (u16*)alloc((size_t)NB * NPX * NC * 2);    // 100.7 MB, live to end
  u16* xC   = (u16*)alloc((size_t)NB * NC * NPX * 2);    // 100.7 MB; G/T/S/At/R/W_eff overlay after G-gemm
  u16* Aq   = (u16*)alloc((size_t)NB * 768 * NC * 2);    // 18.9 MB (q,k rows)
  u16* AvT  = (u16*)alloc((size_t)NB * NC * KS * 2);     // 9.4 MB
  u16* WoS  = (u16*)alloc((size_t)NB * NC * KS * 2);     // 9.4 MB
  float* Gp = (float*)alloc((size_t)2 * NB * 21 * 16384 * 4);  // 44.0 MB; hosts Avtmp early
  float* parts  = (float*)alloc((size_t)NB * NC * 64 * 4);
  float* xmean  = (float*)alloc((size_t)NB * NC * 4);
  float* Y1     = (float*)alloc((size_t)NB * 2304 * 4);
  float* st     = (float*)alloc((size_t)NB * NT * 4);
  float* p      = (float*)alloc((size_t)NB * 1536 * 4);
  float* hid    = (float*)alloc((size_t)NB * 1536 * 4);
  float* pr     = (float*)alloc((size_t)NB * NC * 4);
  int*   idx    = (int*)alloc((size_t)NB * KS * 4);
  float* biasq  = (float*)alloc((size_t)NB * 1152 * 4);
  float* sig    = (float*)alloc((size_t)NB * NC * 4);
  float* bias_fin = (float*)alloc((size_t)NB * NC * 4);

  if (off > ws_size) {
    k_sentinel<<<(out_size + 255) / 256, 256, 0, stream>>>(out, out_size);
    return;
  }

  // overlays
  u16* Avtmp = (u16*)Gp;                                // 9.4 MB, fold -> avt, dead before G-gemm
  u16* G   = (u16*)xC;                                  // 18.9 MB, after G-gemm frees xC
  u16* T   = (u16*)((char*)xC + 20u * 1024 * 1024);     // 9.4 MB
  float* S = (float*)((char*)xC + 32u * 1024 * 1024);   // 9.4 MB
  u16* At  = (u16*)((char*)xC + 44u * 1024 * 1024);     // 4.7 MB
  u16* R   = (u16*)((char*)xC + 52u * 1024 * 1024);     // 9.4 MB
  u16* Wf  = (u16*)((char*)xC + 64u * 1024 * 1024);     // 18.9 MB

  k_trans_mean<<<dim3(64, 12, NB), 256, 0, stream>>>(x, xT, xC, parts);
  k_misc<<<48, 256, 0, stream>>>(parts, xmean, temb, st);
  k_mlp8<<<dim3(96, 2), 256, 0, stream>>>(W_ts, b_ts, st, Y1, 512, 1536, 2304, 0, 0);
  k_mlp8<<<dim3(48, 2), 256, 0, stream>>>(W_tp, b_tp, st, Y1, 512, 768, 2304, 1536, 0);
  k_assemble_p<<<(NB * NC + 255) / 256, 256, 0, stream>>>(Y1, xmean, p);
  k_mlp8<<<dim3(96, 2), 256, 0, stream>>>(W_m1, b_m1, p, hid, 1536, 1536, 1536, 0, 1);
  k_mlp8<<<dim3(48, 2), 256, 0, stream>>>(W_m2, b_m2, hid, pr, 1536, 768, 768, 0, 0);
  k_topk<<<NB, 256, 0, stream>>>(pr, idx);
  k_fold<<<dim3(KS, NB), 256, 0, stream>>>(idx, Y1, xmean, Wq, bq, Wk, bk, Wv, bv,
                                           Aq, Avtmp, biasq, sig);
  k_avt<<<dim3(72, NB), 256, 0, stream>>>(Avtmp, AvT);
  k_gather_wo<<<dim3(96, NB), 256, 0, stream>>>(idx, Wo, WoS);

  // G = xC @ xC^T (symmetric, lower tiles, split-K=2, packed fp32 partials)
  gemm_bt<5><<<dim3(21, 1, NB * 2), 256, 0, stream>>>(
      xC, xC, (size_t)NC * NPX, (size_t)NC * NPX, NPX, NPX, NPX,
      nullptr, 0, Gp, nullptr, 0, 0, nullptr, nullptr, 0.f);
  k_gmerge<<<dim3(21, NB), 256, 0, stream>>>(Gp, G);
  // T = Ak @ G -> bf16 [b][384][768]
  gemm_bt<2><<<dim3(6, 3, NB), 256, 0, stream>>>(
      Aq + (size_t)KS * NC, G, (size_t)768 * NC, (size_t)NC * NC, NC, NC, NC,
      nullptr, 0, nullptr, T, NC, (size_t)KS * NC, nullptr, nullptr, 0.f);
  // S = (Aq @ T^T + rank-1 bias corrections) * scale -> fp32 [b][384][384]
  gemm_bt<1><<<dim3(3, 3, NB), 256, 0, stream>>>(
      Aq, T, (size_t)768 * NC, (size_t)KS * NC, NC, NC, NC,
      nullptr, 0, S, nullptr, KS, (size_t)KS * KS, sig, biasq, 0.05103103630798287f);
  k_softmax<<<dim3(KS, NB), 128, 0, stream>>>(S, At);
  // R = WoS @ attn (Bt = At = attn^T) -> bf16 [b][768][384]
  gemm_bt<2><<<dim3(3, 6, NB), 256, 0, stream>>>(
      WoS, At, (size_t)NC * KS, (size_t)KS * KS, KS, KS, KS,
      nullptr, 0, nullptr, R, KS, (size_t)NC * KS, nullptr, nullptr, 0.f);
  k_bias_fin<<<dim3(48, NB), 256, 0, stream>>>(R, biasq, bo, bias_fin);
  // W_eff = R @ AvT^T -> bf16 [b][768][768]
  gemm_bt<2><<<dim3(6, 6, NB), 256, 0, stream>>>(
      R, AvT, (size_t)NC * KS, (size_t)NC * KS, KS, KS, KS,
      nullptr, 0, nullptr, Wf, NC, (size_t)NC * NC, nullptr, nullptr, 0.f);
  // out = W_eff @ xT^T + bias_fin -> fp32 [b][768][4096]
  gemm_bt<3><<<dim3(32, 6, NB), 256, 0, stream>>>(
      Wf, xT, (size_t)NC * NC, (size_t)NPX * NC, NC, NC, NC,
      bias_fin, NC, out, nullptr, NPX, (size_t)NC * NPX, nullptr, nullptr, 0.f);
}

// Round 7
// 693.211 us; speedup vs baseline: 1.2974x; 1.0063x over previous
//
#include <hip/hip_runtime.h>

#define NB 16
#define NC 768
#define NT 512
#define KS 384
#define NPX 4096
#define BK 64

typedef __bf16 bfx8 __attribute__((ext_vector_type(8)));
typedef float fx4 __attribute__((ext_vector_type(4)));
typedef unsigned short u16;
typedef unsigned short usv4 __attribute__((ext_vector_type(4)));

__device__ __forceinline__ u16 f2bf(float f) {
  unsigned u = __builtin_bit_cast(unsigned, f);
  u += 0x7FFFu + ((u >> 16) & 1u);
  return (u16)(u >> 16);
}
__device__ __forceinline__ float bf2f(u16 v) {
  return __builtin_bit_cast(float, (unsigned)v << 16);
}

__device__ __forceinline__ void gload16(const u16* g, u16* l) {
  __builtin_amdgcn_global_load_lds(
      (const __attribute__((address_space(1))) unsigned int*)g,
      (__attribute__((address_space(3))) unsigned int*)l, 16, 0, 0);
}

// ---- K1: x -> bf16 xT[b][px][c] (transposed) + xC[b][c][px] (cast) + partial sums ----
__global__ void k_trans_mean(const float* __restrict__ x, u16* __restrict__ xT,
                             u16* __restrict__ xC, float* __restrict__ parts) {
  __shared__ float ld[64][65];
  int p0 = blockIdx.x * 64, c0 = blockIdx.y * 64, b = blockIdx.z;
  int t = threadIdx.x;
  int k = t & 15, ir = t >> 4;
  int jr = k * 4;
#pragma unroll
  for (int s = 0; s < 4; ++s) {
    int i = ir + s * 16;
    float4 v = *(const float4*)&x[(size_t)(b * NC + c0 + i) * NPX + p0 + jr];
    ld[i][jr] = v.x; ld[i][jr + 1] = v.y; ld[i][jr + 2] = v.z; ld[i][jr + 3] = v.w;
    usv4 pk = {f2bf(v.x), f2bf(v.y), f2bf(v.z), f2bf(v.w)};
    *(usv4*)&xC[(size_t)(b * NC + c0 + i) * NPX + p0 + jr] = pk;
  }
  __syncthreads();
#pragma unroll
  for (int s = 0; s < 4; ++s) {
    int j = ir + s * 16;
    usv4 pk = {f2bf(ld[k * 4][j]), f2bf(ld[k * 4 + 1][j]),
               f2bf(ld[k * 4 + 2][j]), f2bf(ld[k * 4 + 3][j])};
    *(usv4*)&xT[(size_t)(b * NPX + p0 + j) * NC + c0 + k * 4] = pk;
  }
  if (t < 64) {
    float s = 0.f;
    for (int j = 0; j < 64; ++j) s += ld[t][j];
    parts[(size_t)(b * NC + c0 + t) * 64 + blockIdx.x] = s;
  }
}

// ---- fused: xmean finalize + silu(temb) ----
__global__ void k_misc(const float* __restrict__ parts, float* __restrict__ xmean,
                       const float* __restrict__ temb, float* __restrict__ st) {
  int id = blockIdx.x * 256 + threadIdx.x;
  if (id < NB * NT) { float v = temb[id]; st[id] = v / (1.f + expf(-v)); }
  if (id < NB * NC) {
    float s = 0.f;
    for (int j = 0; j < 64; ++j) s += parts[(size_t)id * 64 + j];
    xmean[id] = s * (1.f / 4096.f);
  }
}

// ---- small batched MLP: wide launch, weights spread across blocks ----
__global__ void k_mlp8(const float* __restrict__ W, const float* __restrict__ bias,
                       const float* __restrict__ X, float* __restrict__ Y,
                       int len, int nj, int ostride, int obase, int dosilu) {
  __shared__ float Xs[8 * 1537];
  int t = threadIdx.x, lane = t & 63, w = t >> 6;
  int b0 = blockIdx.y * 8;
  int ldx = len + 1;
  for (int id = t; id < 8 * len; id += 256) {
    int bb = id / len, s = id - bb * len;
    Xs[bb * ldx + s] = X[(size_t)(b0 + bb) * len + s];
  }
  __syncthreads();
  for (int i = 0; i < 4; ++i) {
    int j = blockIdx.x * 16 + i * 4 + w;
    if (j < nj) {
      float acc[8] = {0, 0, 0, 0, 0, 0, 0, 0};
      for (int s = lane; s < len; s += 64) {
        float wv = W[(size_t)j * len + s];
#pragma unroll
        for (int bb = 0; bb < 8; ++bb) acc[bb] += wv * Xs[bb * ldx + s];
      }
#pragma unroll
      for (int bb = 0; bb < 8; ++bb) {
        float r = acc[bb];
#pragma unroll
        for (int m = 32; m; m >>= 1) r += __shfl_xor(r, m);
        if (lane == 0) {
          r += bias[j];
          if (dosilu) r = r / (1.f + expf(-r));
          Y[(size_t)(b0 + bb) * ostride + obase + j] = r;
        }
      }
    }
  }
}

// ---- p = [gap, tp]; gap = xmean*(1+scale)+shift ----
__global__ void k_assemble_p(const float* __restrict__ Y1, const float* __restrict__ xmean,
                             float* __restrict__ p) {
  int id = blockIdx.x * 256 + threadIdx.x;
  if (id >= NB * NC) return;
  int b = id / NC, c = id - b * NC;
  const float* yb = Y1 + (size_t)b * 2304;
  p[(size_t)b * 1536 + c] = xmean[id] * (1.f + yb[c]) + yb[768 + c];
  p[(size_t)b * 1536 + 768 + c] = yb[1536 + c];
}

// ---- top-k by rank counting ----
__global__ void k_topk(const float* __restrict__ prompt, int* __restrict__ idx) {
  __shared__ float pr[NC];
  int b = blockIdx.x, t = threadIdx.x;
  for (int c = t; c < NC; c += 256) pr[c] = prompt[(size_t)b * NC + c];
  __syncthreads();
  for (int c = t; c < NC; c += 256) {
    float v = pr[c];
    int r = 0;
    for (int c2 = 0; c2 < NC; ++c2) {
      float v2 = pr[c2];
      r += (v2 > v) || (v2 == v && c2 < c);
    }
    if (r < KS) idx[b * KS + r] = c;
  }
}

// ---- fold scale into gathered rows; shift into bias; sigma for S corrections ----
__global__ void k_fold(const int* __restrict__ idx, const float* __restrict__ Y1,
                       const float* __restrict__ xmean,
                       const float* __restrict__ Wq, const float* __restrict__ bq,
                       const float* __restrict__ Wk, const float* __restrict__ bk,
                       const float* __restrict__ Wv, const float* __restrict__ bv,
                       u16* __restrict__ Aq, u16* __restrict__ Avtmp,
                       float* __restrict__ biasq, float* __restrict__ sig) {
  __shared__ float red[5 * 256];
  int k = blockIdx.x, b = blockIdx.y, t = threadIdx.x;
  int row = idx[b * KS + k];
  const float* yb = Y1 + (size_t)b * 2304;
  u16* aq = Aq + (size_t)b * 768 * NC;
  u16* av = Avtmp + (size_t)b * KS * NC;
  float dq = 0.f, dk = 0.f, dv = 0.f, sq = 0.f, sk = 0.f;
  for (int c = t; c < NC; c += 256) {
    float sc = 1.f + yb[c], sh = yb[768 + c];
    float xm = xmean[b * NC + c];
    float wq = Wq[(size_t)row * NC + c];
    float wk = Wk[(size_t)row * NC + c];
    float wv = Wv[(size_t)row * NC + c];
    aq[(size_t)k * NC + c] = f2bf(wq * sc);
    aq[(size_t)(KS + k) * NC + c] = f2bf(wk * sc);
    av[(size_t)k * NC + c] = f2bf(wv * sc);
    dq += wq * sh; dk += wk * sh; dv += wv * sh;
    sq += wq * sc * xm; sk += wk * sc * xm;
  }
  red[t] = dq; red[256 + t] = dk; red[512 + t] = dv; red[768 + t] = sq; red[1024 + t] = sk;
  __syncthreads();
  for (int s = 128; s; s >>= 1) {
    if (t < s) {
#pragma unroll
      for (int q = 0; q < 5; ++q) red[q * 256 + t] += red[q * 256 + t + s];
    }
    __syncthreads();
  }
  if (t == 0) {
    biasq[b * 1152 + k] = bq[row] + red[0];
    biasq[b * 1152 + KS + k] = bk[row] + red[256];
    biasq[b * 1152 + 2 * KS + k] = bv[row] + red[512];
    sig[b * NC + k] = 4096.f * red[768];
    sig[b * NC + KS + k] = 4096.f * red[1024];
  }
}

// ---- transpose Avtmp[b][384][768] -> AvT[b][768][384] ----
__global__ void k_avt(const u16* __restrict__ Avtmp, u16* __restrict__ AvT) {
  __shared__ u16 tl[64][65];
  int lt = blockIdx.x % 6, ct = blockIdx.x / 6, b = blockIdx.y;
  int l0 = lt * 64, c0 = ct * 64, t = threadIdx.x;
#pragma unroll
  for (int s = 0; s < 16; ++s) {
    int id = t + 256 * s;
    int r = id >> 6, c = id & 63;
    tl[r][c] = Avtmp[(size_t)b * KS * NC + (size_t)(l0 + r) * NC + c0 + c];
  }
  __syncthreads();
#pragma unroll
  for (int s = 0; s < 16; ++s) {
    int id = t + 256 * s;
    int r = id >> 6, c = id & 63;
    AvT[(size_t)b * NC * KS + (size_t)(c0 + r) * KS + l0 + c] = tl[c][r];
  }
}

// ---- gather Wo columns ----
__global__ void k_gather_wo(const int* __restrict__ idx, const float* __restrict__ Wo,
                            u16* __restrict__ WoSel) {
  __shared__ int il[KS];
  int b = blockIdx.y, t = threadIdx.x;
  for (int k = t; k < KS; k += 256) il[k] = idx[b * KS + k];
  __syncthreads();
  int o0 = blockIdx.x * 8;
  for (int oo = 0; oo < 8; ++oo) {
    int o = o0 + oo;
    const float* wr = Wo + (size_t)o * NC;
    u16* dst = WoSel + ((size_t)b * NC + o) * KS;
    for (int k = t; k < KS; k += 256) dst[k] = f2bf(wr[il[k]]);
  }
}

// ---- merge 2 Gram split-K partials (packed lower tiles) -> full symmetric bf16 G ----
__global__ void k_gmerge(const float* __restrict__ Gp, u16* __restrict__ G) {
  __shared__ u16 gl[128][130];
  int tt = blockIdx.x, b = blockIdx.y, t = threadIdx.x;
  int i = 0;
  while ((i + 1) * (i + 2) / 2 <= tt) ++i;
  int j = tt - i * (i + 1) / 2;
  const float* p0 = Gp + ((size_t)(0 * NB + b) * 21 + tt) * 16384;
  const float* p1 = Gp + ((size_t)(1 * NB + b) * 21 + tt) * 16384;
#pragma unroll
  for (int s = 0; s < 16; ++s) {
    int id = t + 256 * s;
    int row = id >> 5, col4 = (id & 31) * 4;
    float4 a = *(const float4*)&p0[row * 128 + col4];
    float4 bb = *(const float4*)&p1[row * 128 + col4];
    usv4 pk = {f2bf(a.x + bb.x), f2bf(a.y + bb.y), f2bf(a.z + bb.z), f2bf(a.w + bb.w)};
    gl[row][col4] = pk[0]; gl[row][col4 + 1] = pk[1];
    gl[row][col4 + 2] = pk[2]; gl[row][col4 + 3] = pk[3];
    *(usv4*)&G[((size_t)b * NC + i * 128 + row) * NC + j * 128 + col4] = pk;
  }
  if (i == j) return;
  __syncthreads();
#pragma unroll
  for (int s = 0; s < 16; ++s) {
    int id = t + 256 * s;
    int row = id >> 5, col4 = (id & 31) * 4;
    usv4 pk = {gl[col4][row], gl[col4 + 1][row], gl[col4 + 2][row], gl[col4 + 3][row]};
    *(usv4*)&G[((size_t)b * NC + j * 128 + row) * NC + i * 128 + col4] = pk;
  }
}

// ---- row softmax of S, write transposed bf16 At[b][l][k] ----
__global__ void k_softmax(const float* __restrict__ S, u16* __restrict__ At) {
  __shared__ float sh[2];
  int kk = blockIdx.x, b = blockIdx.y, t = threadIdx.x;  // 128 threads
  const float* srow = S + ((size_t)b * KS + kk) * KS;
  float v[3];
#pragma unroll
  for (int i = 0; i < 3; ++i) v[i] = srow[t + 128 * i];
  float m = fmaxf(fmaxf(v[0], v[1]), v[2]);
#pragma unroll
  for (int s = 32; s; s >>= 1) m = fmaxf(m, __shfl_xor(m, s));
  if ((t & 63) == 0) sh[t >> 6] = m;
  __syncthreads();
  m = fmaxf(sh[0], sh[1]);
  float e[3];
  float sum = 0.f;
#pragma unroll
  for (int i = 0; i < 3; ++i) { e[i] = expf(v[i] - m); sum += e[i]; }
#pragma unroll
  for (int s = 32; s; s >>= 1) sum += __shfl_xor(sum, s);
  __syncthreads();
  if ((t & 63) == 0) sh[t >> 6] = sum;
  __syncthreads();
  sum = sh[0] + sh[1];
  float inv = 1.f / sum;
#pragma unroll
  for (int i = 0; i < 3; ++i) {
    int l = t + 128 * i;
    At[((size_t)b * KS + l) * KS + kk] = f2bf(e[i] * inv);
  }
}

// ---- bias_fin[b][o] = bo[o] + sum_l R[b][o][l] * betav[b][l] ----
__global__ void k_bias_fin(const u16* __restrict__ R, const float* __restrict__ biasq,
                           const float* __restrict__ bo, float* __restrict__ bias_fin) {
  __shared__ float bvl[KS];
  int b = blockIdx.y, t = threadIdx.x, lane = t & 63, w = t >> 6;
  for (int l = t; l < KS; l += 256) bvl[l] = biasq[b * 1152 + 768 + l];
  __syncthreads();
  int o0 = blockIdx.x * 16;
  for (int oo = w; oo < 16; oo += 4) {
    int o = o0 + oo;
    const u16* rr = R + ((size_t)b * NC + o) * KS;
    float acc = 0.f;
#pragma unroll
    for (int e = 0; e < 6; ++e) {
      int l = lane + 64 * e;
      acc += bf2f(rr[l]) * bvl[l];
    }
#pragma unroll
    for (int m = 32; m; m >>= 1) acc += __shfl_xor(acc, m);
    if (lane == 0) bias_fin[b * NC + o] = acc + bo[o];
  }
}

// ---- GEMM C = A @ Bt^T via global_load_lds staging ----
// EPI 1: S fp32 + rank-1 bias corrections, *scale
// EPI 2: bf16 C[b][row][col]
// EPI 3: fp32 C + bias[b][row]; 1D grid (3072), XCD-chunked y-fastest decode
// EPI 5: Gram partial, packed lower-tri tiles, split-K=2; 1D grid (672), XCD-chunked
template <int EPI>
__global__ __launch_bounds__(256, 4) void gemm_bt(
    const u16* __restrict__ A, const u16* __restrict__ Bt, size_t sA, size_t sB,
    int ldA, int ldB, int K, const float* __restrict__ bias, int bstride,
    float* __restrict__ outF, u16* __restrict__ outU, int ldC, size_t sC,
    const float* __restrict__ sigp, const float* __restrict__ bqp, float scale) {
  __shared__ u16 As[128 * BK];
  __shared__ u16 Bs[128 * BK];
  int b, m0 = 0, n0 = 0, kbeg = 0, kend = K, tt = 0, gpart = 0;
  if constexpr (EPI == 5) {
    // XCD-chunked: each XCD owns 4 consecutive z (= 2 batches); A,B share xC[b] K-half (~3.1MB < 4MB L2)
    int f = blockIdx.x;
    int w = (f & 7) * 84 + (f >> 3);
    int z = w / 21; tt = w - z * 21;
    b = z >> 1; gpart = z & 1;
    int ii = 0;
    while ((ii + 1) * (ii + 2) / 2 <= tt) ++ii;
    int jj = tt - ii * (ii + 1) / 2;
    m0 = ii * 128; n0 = jj * 128;
    kbeg = gpart * 2048; kend = kbeg + 2048;
  } else if constexpr (EPI == 3) {
    // XCD-chunked, y-fastest within b: 6 m-blocks reuse each B-tile; Wf[b] (1.18MB) stays L2-hot
    int f = blockIdx.x;
    int w = (f & 7) * 384 + (f >> 3);
    b = w / 192; int r = w - b * 192;
    int xx = r / 6, yy = r - xx * 6;
    m0 = yy * 128; n0 = xx * 128;
  } else {
    b = blockIdx.z; m0 = blockIdx.y * 128; n0 = blockIdx.x * 128;
  }
  const u16* Ab = A + (size_t)b * sA;
  const u16* Bb = Bt + (size_t)b * sB;
  int t = threadIdx.x, lane = t & 63, w = t >> 6;
  int wm = (w >> 1) * 64, wn = (w & 1) * 64;
  int r16 = lane & 15, g = lane >> 4;

  int srow = w * 32 + (lane >> 3);
  int scol = (lane & 7) * 8;
  const u16* Ag = Ab + (size_t)(m0 + srow) * ldA + kbeg + scol;
  const u16* Bg = Bb + (size_t)(n0 + srow) * ldB + kbeg + scol;
  u16* Asl = &As[(w * 32) * BK];
  u16* Bsl = &Bs[(w * 32) * BK];

  fx4 acc[4][4] = {};

  for (int k0 = kbeg; k0 < kend; k0 += BK) {
#pragma unroll
    for (int s = 0; s < 4; ++s) gload16(Ag + (size_t)s * 8 * ldA, Asl + s * 8 * BK);
#pragma unroll
    for (int s = 0; s < 4; ++s) gload16(Bg + (size_t)s * 8 * ldB, Bsl + s * 8 * BK);
    Ag += BK; Bg += BK;
    __syncthreads();
#pragma unroll
    for (int kk = 0; kk < 2; ++kk) {
      bfx8 af[4], bfr[4];
#pragma unroll
      for (int i = 0; i < 4; ++i) {
        af[i] = *(const bfx8*)&As[(wm + i * 16 + r16) * BK + kk * 32 + g * 8];
        bfr[i] = *(const bfx8*)&Bs[(wn + i * 16 + r16) * BK + kk * 32 + g * 8];
      }
#pragma unroll
      for (int i = 0; i < 4; ++i)
#pragma unroll
        for (int j = 0; j < 4; ++j)
          acc[i][j] = __builtin_amdgcn_mfma_f32_16x16x32_bf16(af[i], bfr[j], acc[i][j], 0, 0, 0);
    }
    __syncthreads();
  }

#pragma unroll
  for (int i = 0; i < 4; ++i) {
#pragma unroll
    for (int j = 0; j < 4; ++j) {
      int row = wm + i * 16 + g * 4;   // tile-local
      int col = wn + j * 16 + r16;     // tile-local
      fx4 v = acc[i][j];
      if constexpr (EPI == 1) {        // S with exact bias corrections
        int gc = n0 + col;
        float bk_ = bqp[b * 1152 + 384 + gc];
        float sk_ = sigp[b * NC + 384 + gc];
#pragma unroll
        for (int r = 0; r < 4; ++r) {
          int gr = m0 + row + r;
          float bq_ = bqp[b * 1152 + gr];
          float sq_ = sigp[b * NC + gr];
          float val = (v[r] + bq_ * sk_ + bk_ * sq_ + 4096.f * bq_ * bk_) * scale;
          outF[(size_t)b * sC + (size_t)gr * ldC + gc] = val;
        }
      } else if constexpr (EPI == 2) { // bf16 C
#pragma unroll
        for (int r = 0; r < 4; ++r)
          outU[(size_t)b * sC + (size_t)(m0 + row + r) * ldC + (n0 + col)] = f2bf(v[r]);
      } else if constexpr (EPI == 3) { // fp32 + per-batch bias
#pragma unroll
        for (int r = 0; r < 4; ++r)
          outF[(size_t)b * sC + (size_t)(m0 + row + r) * ldC + (n0 + col)] =
              v[r] + bias[b * bstride + m0 + row + r];
      } else {                         // EPI 5: Gram partial, packed tile
        float* o = outF + ((size_t)(gpart * NB + b) * 21 + tt) * 16384;
#pragma unroll
        for (int r = 0; r < 4; ++r) o[(row + r) * 128 + col] = v[r];
      }
    }
  }
}

__global__ void k_sentinel(float* out, int n) {
  int id = blockIdx.x * 256 + threadIdx.x;
  if (id < n) out[id] = 12345.0f;
}

extern "C" void kernel_launch(void* const* d_in, const int* in_sizes, int n_in,
                              void* d_out, int out_size, void* d_ws, size_t ws_size,
                              hipStream_t stream) {
  const float* x    = (const float*)d_in[0];
  const float* temb = (const float*)d_in[1];
  const float* W_ts = (const float*)d_in[2];
  const float* b_ts = (const float*)d_in[3];
  const float* W_tp = (const float*)d_in[4];
  const float* b_tp = (const float*)d_in[5];
  const float* W_m1 = (const float*)d_in[6];
  const float* b_m1 = (const float*)d_in[7];
  const float* W_m2 = (const float*)d_in[8];
  const float* b_m2 = (const float*)d_in[9];
  const float* Wq = (const float*)d_in[10];
  const float* bq = (const float*)d_in[11];
  const float* Wk = (const float*)d_in[12];
  const float* bk = (const float*)d_in[13];
  const float* Wv = (const float*)d_in[14];
  const float* bv = (const float*)d_in[15];
  const float* Wo = (const float*)d_in[16];
  const float* bo = (const float*)d_in[17];
  float* out = (float*)d_out;

  char* base = (char*)d_ws;
  size_t off = 0;
  auto alloc = [&](size_t bytes) -> char* {
    char* pp = base + off;
    off += (bytes + 255) & ~(size_t)255;
    return pp;
  };
  u16* xT   = (u16*)alloc((size_t)NB * NPX * NC * 2);    // 100.7 MB, live to end
  u16* xC   = (u16*)alloc((size_t)NB * NC * NPX * 2);    // 100.7 MB; G/T/S/At/R/W_eff overlay after G-gemm
  u16* Aq   = (u16*)alloc((size_t)NB * 768 * NC * 2);    // 18.9 MB (q,k rows)
  u16* AvT  = (u16*)alloc((size_t)NB * NC * KS * 2);     // 9.4 MB
  u16* WoS  = (u16*)alloc((size_t)NB * NC * KS * 2);     // 9.4 MB
  float* Gp = (float*)alloc((size_t)2 * NB * 21 * 16384 * 4);  // 44.0 MB; hosts Avtmp early
  float* parts  = (float*)alloc((size_t)NB * NC * 64 * 4);
  float* xmean  = (float*)alloc((size_t)NB * NC * 4);
  float* Y1     = (float*)alloc((size_t)NB * 2304 * 4);
  float* st     = (float*)alloc((size_t)NB * NT * 4);
  float* p      = (float*)alloc((size_t)NB * 1536 * 4);
  float* hid    = (float*)alloc((size_t)NB * 1536 * 4);
  float* pr     = (float*)alloc((size_t)NB * NC * 4);
  int*   idx    = (int*)alloc((size_t)NB * KS * 4);
  float* biasq  = (float*)alloc((size_t)NB * 1152 * 4);
  float* sig    = (float*)alloc((size_t)NB * NC * 4);
  float* bias_fin = (float*)alloc((size_t)NB * NC * 4);

  if (off > ws_size) {
    k_sentinel<<<(out_size + 255) / 256, 256, 0, stream>>>(out, out_size);
    return;
  }

  // overlays
  u16* Avtmp = (u16*)Gp;                                // 9.4 MB, fold -> avt, dead before G-gemm
  u16* G   = (u16*)xC;                                  // 18.9 MB, after G-gemm frees xC
  u16* T   = (u16*)((char*)xC + 20u * 1024 * 1024);     // 9.4 MB
  float* S = (float*)((char*)xC + 32u * 1024 * 1024);   // 9.4 MB
  u16* At  = (u16*)((char*)xC + 44u * 1024 * 1024);     // 4.7 MB
  u16* R   = (u16*)((char*)xC + 52u * 1024 * 1024);     // 9.4 MB
  u16* Wf  = (u16*)((char*)xC + 64u * 1024 * 1024);     // 18.9 MB

  k_trans_mean<<<dim3(64, 12, NB), 256, 0, stream>>>(x, xT, xC, parts);
  k_misc<<<48, 256, 0, stream>>>(parts, xmean, temb, st);
  k_mlp8<<<dim3(96, 2), 256, 0, stream>>>(W_ts, b_ts, st, Y1, 512, 1536, 2304, 0, 0);
  k_mlp8<<<dim3(48, 2), 256, 0, stream>>>(W_tp, b_tp, st, Y1, 512, 768, 2304, 1536, 0);
  k_assemble_p<<<(NB * NC + 255) / 256, 256, 0, stream>>>(Y1, xmean, p);
  k_mlp8<<<dim3(96, 2), 256, 0, stream>>>(W_m1, b_m1, p, hid, 1536, 1536, 1536, 0, 1);
  k_mlp8<<<dim3(48, 2), 256, 0, stream>>>(W_m2, b_m2, hid, pr, 1536, 768, 768, 0, 0);
  k_topk<<<NB, 256, 0, stream>>>(pr, idx);
  k_fold<<<dim3(KS, NB), 256, 0, stream>>>(idx, Y1, xmean, Wq, bq, Wk, bk, Wv, bv,
                                           Aq, Avtmp, biasq, sig);
  k_avt<<<dim3(72, NB), 256, 0, stream>>>(Avtmp, AvT);
  k_gather_wo<<<dim3(96, NB), 256, 0, stream>>>(idx, Wo, WoS);

  // G = xC @ xC^T (symmetric, lower tiles, split-K=2, packed fp32 partials), XCD-swizzled
  gemm_bt<5><<<672, 256, 0, stream>>>(
      xC, xC, (size_t)NC * NPX, (size_t)NC * NPX, NPX, NPX, NPX,
      nullptr, 0, Gp, nullptr, 0, 0, nullptr, nullptr, 0.f);
  k_gmerge<<<dim3(21, NB), 256, 0, stream>>>(Gp, G);
  // T = Ak @ G -> bf16 [b][384][768]
  gemm_bt<2><<<dim3(6, 3, NB), 256, 0, stream>>>(
      Aq + (size_t)KS * NC, G, (size_t)768 * NC, (size_t)NC * NC, NC, NC, NC,
      nullptr, 0, nullptr, T, NC, (size_t)KS * NC, nullptr, nullptr, 0.f);
  // S = (Aq @ T^T + rank-1 bias corrections) * scale -> fp32 [b][384][384]
  gemm_bt<1><<<dim3(3, 3, NB), 256, 0, stream>>>(
      Aq, T, (size_t)768 * NC, (size_t)KS * NC, NC, NC, NC,
      nullptr, 0, S, nullptr, KS, (size_t)KS * KS, sig, biasq, 0.05103103630798287f);
  k_softmax<<<dim3(KS, NB), 128, 0, stream>>>(S, At);
  // R = WoS @ attn (Bt = At = attn^T) -> bf16 [b][768][384]
  gemm_bt<2><<<dim3(3, 6, NB), 256, 0, stream>>>(
      WoS, At, (size_t)NC * KS, (size_t)KS * KS, KS, KS, KS,
      nullptr, 0, nullptr, R, KS, (size_t)NC * KS, nullptr, nullptr, 0.f);
  k_bias_fin<<<dim3(48, NB), 256, 0, stream>>>(R, biasq, bo, bias_fin);
  // W_eff = R @ AvT^T -> bf16 [b][768][768]
  gemm_bt<2><<<dim3(6, 6, NB), 256, 0, stream>>>(
      R, AvT, (size_t)NC * KS, (size_t)NC * KS, KS, KS, KS,
      nullptr, 0, nullptr, Wf, NC, (size_t)NC * NC, nullptr, nullptr, 0.f);
  // out = W_eff @ xT^T + bias_fin -> fp32 [b][768][4096], XCD-swizzled
  gemm_bt<3><<<3072, 256, 0, stream>>>(
      Wf, xT, (size_t)NC * NC, (size_t)NPX * NC, NC, NC, NC,
      bias_fin, NC, out, nullptr, NPX, (size_t)NC * NPX, nullptr, nullptr, 0.f);
}

// Round 8
// 681.905 us; speedup vs baseline: 1.3189x; 1.0166x over previous
//
#include <hip/hip_runtime.h>

#define NB 16
#define NC 768
#define NT 512
#define KS 384
#define NPX 4096
#define BK 64

typedef __bf16 bfx8 __attribute__((ext_vector_type(8)));
typedef float fx4 __attribute__((ext_vector_type(4)));
typedef unsigned short u16;
typedef unsigned short usv4 __attribute__((ext_vector_type(4)));

__device__ __forceinline__ u16 f2bf(float f) {
  unsigned u = __builtin_bit_cast(unsigned, f);
  u += 0x7FFFu + ((u >> 16) & 1u);
  return (u16)(u >> 16);
}
__device__ __forceinline__ float bf2f(u16 v) {
  return __builtin_bit_cast(float, (unsigned)v << 16);
}

__device__ __forceinline__ void gload16(const u16* g, u16* l) {
  __builtin_amdgcn_global_load_lds(
      (const __attribute__((address_space(1))) unsigned int*)g,
      (__attribute__((address_space(3))) unsigned int*)l, 16, 0, 0);
}

// ---- K1: x -> bf16 xT[b][px][c] (transposed) + xC[b][c][px] (cast) + partial sums ----
__global__ void k_trans_mean(const float* __restrict__ x, u16* __restrict__ xT,
                             u16* __restrict__ xC, float* __restrict__ parts) {
  __shared__ float ld[64][65];
  int p0 = blockIdx.x * 64, c0 = blockIdx.y * 64, b = blockIdx.z;
  int t = threadIdx.x;
  int k = t & 15, ir = t >> 4;
  int jr = k * 4;
#pragma unroll
  for (int s = 0; s < 4; ++s) {
    int i = ir + s * 16;
    float4 v = *(const float4*)&x[(size_t)(b * NC + c0 + i) * NPX + p0 + jr];
    ld[i][jr] = v.x; ld[i][jr + 1] = v.y; ld[i][jr + 2] = v.z; ld[i][jr + 3] = v.w;
    usv4 pk = {f2bf(v.x), f2bf(v.y), f2bf(v.z), f2bf(v.w)};
    *(usv4*)&xC[(size_t)(b * NC + c0 + i) * NPX + p0 + jr] = pk;
  }
  __syncthreads();
#pragma unroll
  for (int s = 0; s < 4; ++s) {
    int j = ir + s * 16;
    usv4 pk = {f2bf(ld[k * 4][j]), f2bf(ld[k * 4 + 1][j]),
               f2bf(ld[k * 4 + 2][j]), f2bf(ld[k * 4 + 3][j])};
    *(usv4*)&xT[(size_t)(b * NPX + p0 + j) * NC + c0 + k * 4] = pk;
  }
  if (t < 64) {
    float s = 0.f;
    for (int j = 0; j < 64; ++j) s += ld[t][j];
    parts[(size_t)(b * NC + c0 + t) * 64 + blockIdx.x] = s;
  }
}

// ---- fused: xmean finalize + silu(temb) ----
__global__ void k_misc(const float* __restrict__ parts, float* __restrict__ xmean,
                       const float* __restrict__ temb, float* __restrict__ st) {
  int id = blockIdx.x * 256 + threadIdx.x;
  if (id < NB * NT) { float v = temb[id]; st[id] = v / (1.f + expf(-v)); }
  if (id < NB * NC) {
    float s = 0.f;
    for (int j = 0; j < 64; ++j) s += parts[(size_t)id * 64 + j];
    xmean[id] = s * (1.f / 4096.f);
  }
}

// ---- small batched MLP: wide launch, weights spread across blocks ----
__global__ void k_mlp8(const float* __restrict__ W, const float* __restrict__ bias,
                       const float* __restrict__ X, float* __restrict__ Y,
                       int len, int nj, int ostride, int obase, int dosilu) {
  __shared__ float Xs[8 * 1537];
  int t = threadIdx.x, lane = t & 63, w = t >> 6;
  int b0 = blockIdx.y * 8;
  int ldx = len + 1;
  for (int id = t; id < 8 * len; id += 256) {
    int bb = id / len, s = id - bb * len;
    Xs[bb * ldx + s] = X[(size_t)(b0 + bb) * len + s];
  }
  __syncthreads();
  for (int i = 0; i < 4; ++i) {
    int j = blockIdx.x * 16 + i * 4 + w;
    if (j < nj) {
      float acc[8] = {0, 0, 0, 0, 0, 0, 0, 0};
      for (int s = lane; s < len; s += 64) {
        float wv = W[(size_t)j * len + s];
#pragma unroll
        for (int bb = 0; bb < 8; ++bb) acc[bb] += wv * Xs[bb * ldx + s];
      }
#pragma unroll
      for (int bb = 0; bb < 8; ++bb) {
        float r = acc[bb];
#pragma unroll
        for (int m = 32; m; m >>= 1) r += __shfl_xor(r, m);
        if (lane == 0) {
          r += bias[j];
          if (dosilu) r = r / (1.f + expf(-r));
          Y[(size_t)(b0 + bb) * ostride + obase + j] = r;
        }
      }
    }
  }
}

// ---- p = [gap, tp]; gap = xmean*(1+scale)+shift ----
__global__ void k_assemble_p(const float* __restrict__ Y1, const float* __restrict__ xmean,
                             float* __restrict__ p) {
  int id = blockIdx.x * 256 + threadIdx.x;
  if (id >= NB * NC) return;
  int b = id / NC, c = id - b * NC;
  const float* yb = Y1 + (size_t)b * 2304;
  p[(size_t)b * 1536 + c] = xmean[id] * (1.f + yb[c]) + yb[768 + c];
  p[(size_t)b * 1536 + 768 + c] = yb[1536 + c];
}

// ---- top-k by rank counting ----
__global__ void k_topk(const float* __restrict__ prompt, int* __restrict__ idx) {
  __shared__ float pr[NC];
  int b = blockIdx.x, t = threadIdx.x;
  for (int c = t; c < NC; c += 256) pr[c] = prompt[(size_t)b * NC + c];
  __syncthreads();
  for (int c = t; c < NC; c += 256) {
    float v = pr[c];
    int r = 0;
    for (int c2 = 0; c2 < NC; ++c2) {
      float v2 = pr[c2];
      r += (v2 > v) || (v2 == v && c2 < c);
    }
    if (r < KS) idx[b * KS + r] = c;
  }
}

// ---- fold scale into gathered rows; shift into bias; sigma for S corrections ----
__global__ void k_fold(const int* __restrict__ idx, const float* __restrict__ Y1,
                       const float* __restrict__ xmean,
                       const float* __restrict__ Wq, const float* __restrict__ bq,
                       const float* __restrict__ Wk, const float* __restrict__ bk,
                       const float* __restrict__ Wv, const float* __restrict__ bv,
                       u16* __restrict__ Aq, u16* __restrict__ Avtmp,
                       float* __restrict__ biasq, float* __restrict__ sig) {
  __shared__ float red[5 * 256];
  int k = blockIdx.x, b = blockIdx.y, t = threadIdx.x;
  int row = idx[b * KS + k];
  const float* yb = Y1 + (size_t)b * 2304;
  u16* aq = Aq + (size_t)b * 768 * NC;
  u16* av = Avtmp + (size_t)b * KS * NC;
  float dq = 0.f, dk = 0.f, dv = 0.f, sq = 0.f, sk = 0.f;
  for (int c = t; c < NC; c += 256) {
    float sc = 1.f + yb[c], sh = yb[768 + c];
    float xm = xmean[b * NC + c];
    float wq = Wq[(size_t)row * NC + c];
    float wk = Wk[(size_t)row * NC + c];
    float wv = Wv[(size_t)row * NC + c];
    aq[(size_t)k * NC + c] = f2bf(wq * sc);
    aq[(size_t)(KS + k) * NC + c] = f2bf(wk * sc);
    av[(size_t)k * NC + c] = f2bf(wv * sc);
    dq += wq * sh; dk += wk * sh; dv += wv * sh;
    sq += wq * sc * xm; sk += wk * sc * xm;
  }
  red[t] = dq; red[256 + t] = dk; red[512 + t] = dv; red[768 + t] = sq; red[1024 + t] = sk;
  __syncthreads();
  for (int s = 128; s; s >>= 1) {
    if (t < s) {
#pragma unroll
      for (int q = 0; q < 5; ++q) red[q * 256 + t] += red[q * 256 + t + s];
    }
    __syncthreads();
  }
  if (t == 0) {
    biasq[b * 1152 + k] = bq[row] + red[0];
    biasq[b * 1152 + KS + k] = bk[row] + red[256];
    biasq[b * 1152 + 2 * KS + k] = bv[row] + red[512];
    sig[b * NC + k] = 4096.f * red[768];
    sig[b * NC + KS + k] = 4096.f * red[1024];
  }
}

// ---- transpose Avtmp[b][384][768] -> AvT[b][768][384] ----
__global__ void k_avt(const u16* __restrict__ Avtmp, u16* __restrict__ AvT) {
  __shared__ u16 tl[64][65];
  int lt = blockIdx.x % 6, ct = blockIdx.x / 6, b = blockIdx.y;
  int l0 = lt * 64, c0 = ct * 64, t = threadIdx.x;
#pragma unroll
  for (int s = 0; s < 16; ++s) {
    int id = t + 256 * s;
    int r = id >> 6, c = id & 63;
    tl[r][c] = Avtmp[(size_t)b * KS * NC + (size_t)(l0 + r) * NC + c0 + c];
  }
  __syncthreads();
#pragma unroll
  for (int s = 0; s < 16; ++s) {
    int id = t + 256 * s;
    int r = id >> 6, c = id & 63;
    AvT[(size_t)b * NC * KS + (size_t)(c0 + r) * KS + l0 + c] = tl[c][r];
  }
}

// ---- gather Wo columns ----
__global__ void k_gather_wo(const int* __restrict__ idx, const float* __restrict__ Wo,
                            u16* __restrict__ WoSel) {
  __shared__ int il[KS];
  int b = blockIdx.y, t = threadIdx.x;
  for (int k = t; k < KS; k += 256) il[k] = idx[b * KS + k];
  __syncthreads();
  int o0 = blockIdx.x * 8;
  for (int oo = 0; oo < 8; ++oo) {
    int o = o0 + oo;
    const float* wr = Wo + (size_t)o * NC;
    u16* dst = WoSel + ((size_t)b * NC + o) * KS;
    for (int k = t; k < KS; k += 256) dst[k] = f2bf(wr[il[k]]);
  }
}

// ---- merge 2 Gram split-K partials (packed lower tiles) -> full symmetric bf16 G ----
__global__ void k_gmerge(const float* __restrict__ Gp, u16* __restrict__ G) {
  __shared__ u16 gl[128][130];
  int tt = blockIdx.x, b = blockIdx.y, t = threadIdx.x;
  int i = 0;
  while ((i + 1) * (i + 2) / 2 <= tt) ++i;
  int j = tt - i * (i + 1) / 2;
  const float* p0 = Gp + ((size_t)(0 * NB + b) * 21 + tt) * 16384;
  const float* p1 = Gp + ((size_t)(1 * NB + b) * 21 + tt) * 16384;
#pragma unroll
  for (int s = 0; s < 16; ++s) {
    int id = t + 256 * s;
    int row = id >> 5, col4 = (id & 31) * 4;
    float4 a = *(const float4*)&p0[row * 128 + col4];
    float4 bb = *(const float4*)&p1[row * 128 + col4];
    usv4 pk = {f2bf(a.x + bb.x), f2bf(a.y + bb.y), f2bf(a.z + bb.z), f2bf(a.w + bb.w)};
    gl[row][col4] = pk[0]; gl[row][col4 + 1] = pk[1];
    gl[row][col4 + 2] = pk[2]; gl[row][col4 + 3] = pk[3];
    *(usv4*)&G[((size_t)b * NC + i * 128 + row) * NC + j * 128 + col4] = pk;
  }
  if (i == j) return;
  __syncthreads();
#pragma unroll
  for (int s = 0; s < 16; ++s) {
    int id = t + 256 * s;
    int row = id >> 5, col4 = (id & 31) * 4;
    usv4 pk = {gl[col4][row], gl[col4 + 1][row], gl[col4 + 2][row], gl[col4 + 3][row]};
    *(usv4*)&G[((size_t)b * NC + j * 128 + row) * NC + i * 128 + col4] = pk;
  }
}

// ---- row softmax of S, write transposed bf16 At[b][l][k] ----
__global__ void k_softmax(const float* __restrict__ S, u16* __restrict__ At) {
  __shared__ float sh[2];
  int kk = blockIdx.x, b = blockIdx.y, t = threadIdx.x;  // 128 threads
  const float* srow = S + ((size_t)b * KS + kk) * KS;
  float v[3];
#pragma unroll
  for (int i = 0; i < 3; ++i) v[i] = srow[t + 128 * i];
  float m = fmaxf(fmaxf(v[0], v[1]), v[2]);
#pragma unroll
  for (int s = 32; s; s >>= 1) m = fmaxf(m, __shfl_xor(m, s));
  if ((t & 63) == 0) sh[t >> 6] = m;
  __syncthreads();
  m = fmaxf(sh[0], sh[1]);
  float e[3];
  float sum = 0.f;
#pragma unroll
  for (int i = 0; i < 3; ++i) { e[i] = expf(v[i] - m); sum += e[i]; }
#pragma unroll
  for (int s = 32; s; s >>= 1) sum += __shfl_xor(sum, s);
  __syncthreads();
  if ((t & 63) == 0) sh[t >> 6] = sum;
  __syncthreads();
  sum = sh[0] + sh[1];
  float inv = 1.f / sum;
#pragma unroll
  for (int i = 0; i < 3; ++i) {
    int l = t + 128 * i;
    At[((size_t)b * KS + l) * KS + kk] = f2bf(e[i] * inv);
  }
}

// ---- bias_fin[b][o] = bo[o] + sum_l R[b][o][l] * betav[b][l] ----
__global__ void k_bias_fin(const u16* __restrict__ R, const float* __restrict__ biasq,
                           const float* __restrict__ bo, float* __restrict__ bias_fin) {
  __shared__ float bvl[KS];
  int b = blockIdx.y, t = threadIdx.x, lane = t & 63, w = t >> 6;
  for (int l = t; l < KS; l += 256) bvl[l] = biasq[b * 1152 + 768 + l];
  __syncthreads();
  int o0 = blockIdx.x * 16;
  for (int oo = w; oo < 16; oo += 4) {
    int o = o0 + oo;
    const u16* rr = R + ((size_t)b * NC + o) * KS;
    float acc = 0.f;
#pragma unroll
    for (int e = 0; e < 6; ++e) {
      int l = lane + 64 * e;
      acc += bf2f(rr[l]) * bvl[l];
    }
#pragma unroll
    for (int m = 32; m; m >>= 1) acc += __shfl_xor(acc, m);
    if (lane == 0) bias_fin[b * NC + o] = acc + bo[o];
  }
}

// ---- GEMM C = A @ Bt^T via global_load_lds staging, XOR-swizzled LDS (T2 via
//      pre-swizzled global source: LDS granule slot s of row r holds logical
//      granule s^(r&7); reads XOR the same way -> 16-way bank conflict -> 2-way) ----
// EPI 1: S fp32 + rank-1 bias corrections, *scale
// EPI 2: bf16 C[b][row][col]
// EPI 3: fp32 C + bias[b][row]; 1D grid (3072), XCD-chunked y-fastest decode
// EPI 5: Gram partial, packed lower-tri tiles, split-K=2; 1D grid (672), XCD-chunked
template <int EPI>
__global__ __launch_bounds__(256, 4) void gemm_bt(
    const u16* __restrict__ A, const u16* __restrict__ Bt, size_t sA, size_t sB,
    int ldA, int ldB, int K, const float* __restrict__ bias, int bstride,
    float* __restrict__ outF, u16* __restrict__ outU, int ldC, size_t sC,
    const float* __restrict__ sigp, const float* __restrict__ bqp, float scale) {
  __shared__ u16 As[128 * BK];
  __shared__ u16 Bs[128 * BK];
  int b, m0 = 0, n0 = 0, kbeg = 0, kend = K, tt = 0, gpart = 0;
  if constexpr (EPI == 5) {
    int f = blockIdx.x;
    int w = (f & 7) * 84 + (f >> 3);
    int z = w / 21; tt = w - z * 21;
    b = z >> 1; gpart = z & 1;
    int ii = 0;
    while ((ii + 1) * (ii + 2) / 2 <= tt) ++ii;
    int jj = tt - ii * (ii + 1) / 2;
    m0 = ii * 128; n0 = jj * 128;
    kbeg = gpart * 2048; kend = kbeg + 2048;
  } else if constexpr (EPI == 3) {
    int f = blockIdx.x;
    int w = (f & 7) * 384 + (f >> 3);
    b = w / 192; int r = w - b * 192;
    int xx = r / 6, yy = r - xx * 6;
    m0 = yy * 128; n0 = xx * 128;
  } else {
    b = blockIdx.z; m0 = blockIdx.y * 128; n0 = blockIdx.x * 128;
  }
  const u16* Ab = A + (size_t)b * sA;
  const u16* Bb = Bt + (size_t)b * sB;
  int t = threadIdx.x, lane = t & 63, w = t >> 6;
  int wm = (w >> 1) * 64, wn = (w & 1) * 64;
  int r16 = lane & 15, g = lane >> 4;

  int srow = w * 32 + (lane >> 3);
  // pre-swizzled source column: LDS slot (lane&7) of row gets logical granule (lane&7)^(lane>>3)
  int scol = (((lane & 7) ^ (lane >> 3)) & 7) * 8;
  const u16* Ag = Ab + (size_t)(m0 + srow) * ldA + kbeg + scol;
  const u16* Bg = Bb + (size_t)(n0 + srow) * ldB + kbeg + scol;
  u16* Asl = &As[(w * 32) * BK];
  u16* Bsl = &Bs[(w * 32) * BK];

  fx4 acc[4][4] = {};

  for (int k0 = kbeg; k0 < kend; k0 += BK) {
#pragma unroll
    for (int s = 0; s < 4; ++s) gload16(Ag + (size_t)s * 8 * ldA, Asl + s * 8 * BK);
#pragma unroll
    for (int s = 0; s < 4; ++s) gload16(Bg + (size_t)s * 8 * ldB, Bsl + s * 8 * BK);
    Ag += BK; Bg += BK;
    __syncthreads();
#pragma unroll
    for (int kk = 0; kk < 2; ++kk) {
      bfx8 af[4], bfr[4];
      int swz = ((kk * 4 + g) ^ (r16 & 7)) * 8;  // swizzled read granule
#pragma unroll
      for (int i = 0; i < 4; ++i) {
        af[i] = *(const bfx8*)&As[(wm + i * 16 + r16) * BK + swz];
        bfr[i] = *(const bfx8*)&Bs[(wn + i * 16 + r16) * BK + swz];
      }
#pragma unroll
      for (int i = 0; i < 4; ++i)
#pragma unroll
        for (int j = 0; j < 4; ++j)
          acc[i][j] = __builtin_amdgcn_mfma_f32_16x16x32_bf16(af[i], bfr[j], acc[i][j], 0, 0, 0);
    }
    __syncthreads();
  }

#pragma unroll
  for (int i = 0; i < 4; ++i) {
#pragma unroll
    for (int j = 0; j < 4; ++j) {
      int row = wm + i * 16 + g * 4;   // tile-local
      int col = wn + j * 16 + r16;     // tile-local
      fx4 v = acc[i][j];
      if constexpr (EPI == 1) {        // S with exact bias corrections
        int gc = n0 + col;
        float bk_ = bqp[b * 1152 + 384 + gc];
        float sk_ = sigp[b * NC + 384 + gc];
#pragma unroll
        for (int r = 0; r < 4; ++r) {
          int gr = m0 + row + r;
          float bq_ = bqp[b * 1152 + gr];
          float sq_ = sigp[b * NC + gr];
          float val = (v[r] + bq_ * sk_ + bk_ * sq_ + 4096.f * bq_ * bk_) * scale;
          outF[(size_t)b * sC + (size_t)gr * ldC + gc] = val;
        }
      } else if constexpr (EPI == 2) { // bf16 C
#pragma unroll
        for (int r = 0; r < 4; ++r)
          outU[(size_t)b * sC + (size_t)(m0 + row + r) * ldC + (n0 + col)] = f2bf(v[r]);
      } else if constexpr (EPI == 3) { // fp32 + per-batch bias
#pragma unroll
        for (int r = 0; r < 4; ++r)
          outF[(size_t)b * sC + (size_t)(m0 + row + r) * ldC + (n0 + col)] =
              v[r] + bias[b * bstride + m0 + row + r];
      } else {                         // EPI 5: Gram partial, packed tile
        float* o = outF + ((size_t)(gpart * NB + b) * 21 + tt) * 16384;
#pragma unroll
        for (int r = 0; r < 4; ++r) o[(row + r) * 128 + col] = v[r];
      }
    }
  }
}

__global__ void k_sentinel(float* out, int n) {
  int id = blockIdx.x * 256 + threadIdx.x;
  if (id < n) out[id] = 12345.0f;
}

extern "C" void kernel_launch(void* const* d_in, const int* in_sizes, int n_in,
                              void* d_out, int out_size, void* d_ws, size_t ws_size,
                              hipStream_t stream) {
  const float* x    = (const float*)d_in[0];
  const float* temb = (const float*)d_in[1];
  const float* W_ts = (const float*)d_in[2];
  const float* b_ts = (const float*)d_in[3];
  const float* W_tp = (const float*)d_in[4];
  const float* b_tp = (const float*)d_in[5];
  const float* W_m1 = (const float*)d_in[6];
  const float* b_m1 = (const float*)d_in[7];
  const float* W_m2 = (const float*)d_in[8];
  const float* b_m2 = (const float*)d_in[9];
  const float* Wq = (const float*)d_in[10];
  const float* bq = (const float*)d_in[11];
  const float* Wk = (const float*)d_in[12];
  const float* bk = (const float*)d_in[13];
  const float* Wv = (const float*)d_in[14];
  const float* bv = (const float*)d_in[15];
  const float* Wo = (const float*)d_in[16];
  const float* bo = (const float*)d_in[17];
  float* out = (float*)d_out;

  char* base = (char*)d_ws;
  size_t off = 0;
  auto alloc = [&](size_t bytes) -> char* {
    char* pp = base + off;
    off += (bytes + 255) & ~(size_t)255;
    return pp;
  };
  u16* xT   = (u16*)alloc((size_t)NB * NPX * NC * 2);    // 100.7 MB, live to end
  u16* xC   = (u16*)alloc((size_t)NB * NC * NPX * 2);    // 100.7 MB; G/T/S/At/R/W_eff overlay after G-gemm
  u16* Aq   = (u16*)alloc((size_t)NB * 768 * NC * 2);    // 18.9 MB (q,k rows)
  u16* AvT  = (u16*)alloc((size_t)NB * NC * KS * 2);     // 9.4 MB
  u16* WoS  = (u16*)alloc((size_t)NB * NC * KS * 2);     // 9.4 MB
  float* Gp = (float*)alloc((size_t)2 * NB * 21 * 16384 * 4);  // 44.0 MB; hosts Avtmp early
  float* parts  = (float*)alloc((size_t)NB * NC * 64 * 4);
  float* xmean  = (float*)alloc((size_t)NB * NC * 4);
  float* Y1     = (float*)alloc((size_t)NB * 2304 * 4);
  float* st     = (float*)alloc((size_t)NB * NT * 4);
  float* p      = (float*)alloc((size_t)NB * 1536 * 4);
  float* hid    = (float*)alloc((size_t)NB * 1536 * 4);
  float* pr     = (float*)alloc((size_t)NB * NC * 4);
  int*   idx    = (int*)alloc((size_t)NB * KS * 4);
  float* biasq  = (float*)alloc((size_t)NB * 1152 * 4);
  float* sig    = (float*)alloc((size_t)NB * NC * 4);
  float* bias_fin = (float*)alloc((size_t)NB * NC * 4);

  if (off > ws_size) {
    k_sentinel<<<(out_size + 255) / 256, 256, 0, stream>>>(out, out_size);
    return;
  }

  // overlays
  u16* Avtmp = (u16*)Gp;                                // 9.4 MB, fold -> avt, dead before G-gemm
  u16* G   = (u16*)xC;                                  // 18.9 MB, after G-gemm frees xC
  u16* T   = (u16*)((char*)xC + 20u * 1024 * 1024);     // 9.4 MB
  float* S = (float*)((char*)xC + 32u * 1024 * 1024);   // 9.4 MB
  u16* At  = (u16*)((char*)xC + 44u * 1024 * 1024);     // 4.7 MB
  u16* R   = (u16*)((char*)xC + 52u * 1024 * 1024);     // 9.4 MB
  u16* Wf  = (u16*)((char*)xC + 64u * 1024 * 1024);     // 18.9 MB

  k_trans_mean<<<dim3(64, 12, NB), 256, 0, stream>>>(x, xT, xC, parts);
  k_misc<<<48, 256, 0, stream>>>(parts, xmean, temb, st);
  k_mlp8<<<dim3(96, 2), 256, 0, stream>>>(W_ts, b_ts, st, Y1, 512, 1536, 2304, 0, 0);
  k_mlp8<<<dim3(48, 2), 256, 0, stream>>>(W_tp, b_tp, st, Y1, 512, 768, 2304, 1536, 0);
  k_assemble_p<<<(NB * NC + 255) / 256, 256, 0, stream>>>(Y1, xmean, p);
  k_mlp8<<<dim3(96, 2), 256, 0, stream>>>(W_m1, b_m1, p, hid, 1536, 1536, 1536, 0, 1);
  k_mlp8<<<dim3(48, 2), 256, 0, stream>>>(W_m2, b_m2, hid, pr, 1536, 768, 768, 0, 0);
  k_topk<<<NB, 256, 0, stream>>>(pr, idx);
  k_fold<<<dim3(KS, NB), 256, 0, stream>>>(idx, Y1, xmean, Wq, bq, Wk, bk, Wv, bv,
                                           Aq, Avtmp, biasq, sig);
  k_avt<<<dim3(72, NB), 256, 0, stream>>>(Avtmp, AvT);
  k_gather_wo<<<dim3(96, NB), 256, 0, stream>>>(idx, Wo, WoS);

  // G = xC @ xC^T (symmetric, lower tiles, split-K=2, packed fp32 partials), XCD-swizzled
  gemm_bt<5><<<672, 256, 0, stream>>>(
      xC, xC, (size_t)NC * NPX, (size_t)NC * NPX, NPX, NPX, NPX,
      nullptr, 0, Gp, nullptr, 0, 0, nullptr, nullptr, 0.f);
  k_gmerge<<<dim3(21, NB), 256, 0, stream>>>(Gp, G);
  // T = Ak @ G -> bf16 [b][384][768]
  gemm_bt<2><<<dim3(6, 3, NB), 256, 0, stream>>>(
      Aq + (size_t)KS * NC, G, (size_t)768 * NC, (size_t)NC * NC, NC, NC, NC,
      nullptr, 0, nullptr, T, NC, (size_t)KS * NC, nullptr, nullptr, 0.f);
  // S = (Aq @ T^T + rank-1 bias corrections) * scale -> fp32 [b][384][384]
  gemm_bt<1><<<dim3(3, 3, NB), 256, 0, stream>>>(
      Aq, T, (size_t)768 * NC, (size_t)KS * NC, NC, NC, NC,
      nullptr, 0, S, nullptr, KS, (size_t)KS * KS, sig, biasq, 0.05103103630798287f);
  k_softmax<<<dim3(KS, NB), 128, 0, stream>>>(S, At);
  // R = WoS @ attn (Bt = At = attn^T) -> bf16 [b][768][384]
  gemm_bt<2><<<dim3(3, 6, NB), 256, 0, stream>>>(
      WoS, At, (size_t)NC * KS, (size_t)KS * KS, KS, KS, KS,
      nullptr, 0, nullptr, R, KS, (size_t)NC * KS, nullptr, nullptr, 0.f);
  k_bias_fin<<<dim3(48, NB), 256, 0, stream>>>(R, biasq, bo, bias_fin);
  // W_eff = R @ AvT^T -> bf16 [b][768][768]
  gemm_bt<2><<<dim3(6, 6, NB), 256, 0, stream>>>(
      R, AvT, (size_t)NC * KS, (size_t)NC * KS, KS, KS, KS,
      nullptr, 0, nullptr, Wf, NC, (size_t)NC * NC, nullptr, nullptr, 0.f);
  // out = W_eff @ xT^T + bias_fin -> fp32 [b][768][4096], XCD-swizzled
  gemm_bt<3><<<3072, 256, 0, stream>>>(
      Wf, xT, (size_t)NC * NC, (size_t)NPX * NC, NC, NC, NC,
      bias_fin, NC, out, nullptr, NPX, (size_t)NC * NPX, nullptr, nullptr, 0.f);
}

// Round 9
// 654.526 us; speedup vs baseline: 1.3740x; 1.0418x over previous
//
#include <hip/hip_runtime.h>

#define NB 16
#define NC 768
#define NT 512
#define KS 384
#define NPX 4096
#define BK 64

typedef __bf16 bfx8 __attribute__((ext_vector_type(8)));
typedef float fx4 __attribute__((ext_vector_type(4)));
typedef unsigned short u16;
typedef unsigned short usv4 __attribute__((ext_vector_type(4)));

__device__ __forceinline__ u16 f2bf(float f) {
  unsigned u = __builtin_bit_cast(unsigned, f);
  u += 0x7FFFu + ((u >> 16) & 1u);
  return (u16)(u >> 16);
}
__device__ __forceinline__ float bf2f(u16 v) {
  return __builtin_bit_cast(float, (unsigned)v << 16);
}

__device__ __forceinline__ void gload16(const u16* g, u16* l) {
  __builtin_amdgcn_global_load_lds(
      (const __attribute__((address_space(1))) unsigned int*)g,
      (__attribute__((address_space(3))) unsigned int*)l, 16, 0, 0);
}

// ---- K1: x -> bf16 xT[b][px][c] (transposed) + xC[b][c][px] (cast) + partial sums ----
__global__ void k_trans_mean(const float* __restrict__ x, u16* __restrict__ xT,
                             u16* __restrict__ xC, float* __restrict__ parts) {
  __shared__ float ld[64][65];
  int p0 = blockIdx.x * 64, c0 = blockIdx.y * 64, b = blockIdx.z;
  int t = threadIdx.x;
  int k = t & 15, ir = t >> 4;
  int jr = k * 4;
#pragma unroll
  for (int s = 0; s < 4; ++s) {
    int i = ir + s * 16;
    float4 v = *(const float4*)&x[(size_t)(b * NC + c0 + i) * NPX + p0 + jr];
    ld[i][jr] = v.x; ld[i][jr + 1] = v.y; ld[i][jr + 2] = v.z; ld[i][jr + 3] = v.w;
    usv4 pk = {f2bf(v.x), f2bf(v.y), f2bf(v.z), f2bf(v.w)};
    *(usv4*)&xC[(size_t)(b * NC + c0 + i) * NPX + p0 + jr] = pk;
  }
  __syncthreads();
#pragma unroll
  for (int s = 0; s < 4; ++s) {
    int j = ir + s * 16;
    usv4 pk = {f2bf(ld[k * 4][j]), f2bf(ld[k * 4 + 1][j]),
               f2bf(ld[k * 4 + 2][j]), f2bf(ld[k * 4 + 3][j])};
    *(usv4*)&xT[(size_t)(b * NPX + p0 + j) * NC + c0 + k * 4] = pk;
  }
  if (t < 64) {
    float s = 0.f;
    for (int j = 0; j < 64; ++j) s += ld[t][j];
    parts[(size_t)(b * NC + c0 + t) * 64 + blockIdx.x] = s;
  }
}

// ---- fused: xmean finalize + silu(temb) ----
__global__ void k_misc(const float* __restrict__ parts, float* __restrict__ xmean,
                       const float* __restrict__ temb, float* __restrict__ st) {
  int id = blockIdx.x * 256 + threadIdx.x;
  if (id < NB * NT) { float v = temb[id]; st[id] = v / (1.f + expf(-v)); }
  if (id < NB * NC) {
    float s = 0.f;
    for (int j = 0; j < 64; ++j) s += parts[(size_t)id * 64 + j];
    xmean[id] = s * (1.f / 4096.f);
  }
}

// ---- small batched MLP: wide launch, weights spread across blocks ----
__global__ void k_mlp8(const float* __restrict__ W, const float* __restrict__ bias,
                       const float* __restrict__ X, float* __restrict__ Y,
                       int len, int nj, int ostride, int obase, int dosilu) {
  __shared__ float Xs[8 * 1537];
  int t = threadIdx.x, lane = t & 63, w = t >> 6;
  int b0 = blockIdx.y * 8;
  int ldx = len + 1;
  for (int id = t; id < 8 * len; id += 256) {
    int bb = id / len, s = id - bb * len;
    Xs[bb * ldx + s] = X[(size_t)(b0 + bb) * len + s];
  }
  __syncthreads();
  for (int i = 0; i < 4; ++i) {
    int j = blockIdx.x * 16 + i * 4 + w;
    if (j < nj) {
      float acc[8] = {0, 0, 0, 0, 0, 0, 0, 0};
      for (int s = lane; s < len; s += 64) {
        float wv = W[(size_t)j * len + s];
#pragma unroll
        for (int bb = 0; bb < 8; ++bb) acc[bb] += wv * Xs[bb * ldx + s];
      }
#pragma unroll
      for (int bb = 0; bb < 8; ++bb) {
        float r = acc[bb];
#pragma unroll
        for (int m = 32; m; m >>= 1) r += __shfl_xor(r, m);
        if (lane == 0) {
          r += bias[j];
          if (dosilu) r = r / (1.f + expf(-r));
          Y[(size_t)(b0 + bb) * ostride + obase + j] = r;
        }
      }
    }
  }
}

// ---- p = [gap, tp]; gap = xmean*(1+scale)+shift ----
__global__ void k_assemble_p(const float* __restrict__ Y1, const float* __restrict__ xmean,
                             float* __restrict__ p) {
  int id = blockIdx.x * 256 + threadIdx.x;
  if (id >= NB * NC) return;
  int b = id / NC, c = id - b * NC;
  const float* yb = Y1 + (size_t)b * 2304;
  p[(size_t)b * 1536 + c] = xmean[id] * (1.f + yb[c]) + yb[768 + c];
  p[(size_t)b * 1536 + 768 + c] = yb[1536 + c];
}

// ---- top-k by rank counting ----
__global__ void k_topk(const float* __restrict__ prompt, int* __restrict__ idx) {
  __shared__ float pr[NC];
  int b = blockIdx.x, t = threadIdx.x;
  for (int c = t; c < NC; c += 256) pr[c] = prompt[(size_t)b * NC + c];
  __syncthreads();
  for (int c = t; c < NC; c += 256) {
    float v = pr[c];
    int r = 0;
    for (int c2 = 0; c2 < NC; ++c2) {
      float v2 = pr[c2];
      r += (v2 > v) || (v2 == v && c2 < c);
    }
    if (r < KS) idx[b * KS + r] = c;
  }
}

// ---- fold scale into gathered rows; shift into bias; sigma for S corrections ----
__global__ void k_fold(const int* __restrict__ idx, const float* __restrict__ Y1,
                       const float* __restrict__ xmean,
                       const float* __restrict__ Wq, const float* __restrict__ bq,
                       const float* __restrict__ Wk, const float* __restrict__ bk,
                       const float* __restrict__ Wv, const float* __restrict__ bv,
                       u16* __restrict__ Aq, u16* __restrict__ Avtmp,
                       float* __restrict__ biasq, float* __restrict__ sig) {
  __shared__ float red[5 * 256];
  int k = blockIdx.x, b = blockIdx.y, t = threadIdx.x;
  int row = idx[b * KS + k];
  const float* yb = Y1 + (size_t)b * 2304;
  u16* aq = Aq + (size_t)b * 768 * NC;
  u16* av = Avtmp + (size_t)b * KS * NC;
  float dq = 0.f, dk = 0.f, dv = 0.f, sq = 0.f, sk = 0.f;
  for (int c = t; c < NC; c += 256) {
    float sc = 1.f + yb[c], sh = yb[768 + c];
    float xm = xmean[b * NC + c];
    float wq = Wq[(size_t)row * NC + c];
    float wk = Wk[(size_t)row * NC + c];
    float wv = Wv[(size_t)row * NC + c];
    aq[(size_t)k * NC + c] = f2bf(wq * sc);
    aq[(size_t)(KS + k) * NC + c] = f2bf(wk * sc);
    av[(size_t)k * NC + c] = f2bf(wv * sc);
    dq += wq * sh; dk += wk * sh; dv += wv * sh;
    sq += wq * sc * xm; sk += wk * sc * xm;
  }
  red[t] = dq; red[256 + t] = dk; red[512 + t] = dv; red[768 + t] = sq; red[1024 + t] = sk;
  __syncthreads();
  for (int s = 128; s; s >>= 1) {
    if (t < s) {
#pragma unroll
      for (int q = 0; q < 5; ++q) red[q * 256 + t] += red[q * 256 + t + s];
    }
    __syncthreads();
  }
  if (t == 0) {
    biasq[b * 1152 + k] = bq[row] + red[0];
    biasq[b * 1152 + KS + k] = bk[row] + red[256];
    biasq[b * 1152 + 2 * KS + k] = bv[row] + red[512];
    sig[b * NC + k] = 4096.f * red[768];
    sig[b * NC + KS + k] = 4096.f * red[1024];
  }
}

// ---- transpose Avtmp[b][384][768] -> AvT[b][768][384] ----
__global__ void k_avt(const u16* __restrict__ Avtmp, u16* __restrict__ AvT) {
  __shared__ u16 tl[64][65];
  int lt = blockIdx.x % 6, ct = blockIdx.x / 6, b = blockIdx.y;
  int l0 = lt * 64, c0 = ct * 64, t = threadIdx.x;
#pragma unroll
  for (int s = 0; s < 16; ++s) {
    int id = t + 256 * s;
    int r = id >> 6, c = id & 63;
    tl[r][c] = Avtmp[(size_t)b * KS * NC + (size_t)(l0 + r) * NC + c0 + c];
  }
  __syncthreads();
#pragma unroll
  for (int s = 0; s < 16; ++s) {
    int id = t + 256 * s;
    int r = id >> 6, c = id & 63;
    AvT[(size_t)b * NC * KS + (size_t)(c0 + r) * KS + l0 + c] = tl[c][r];
  }
}

// ---- gather Wo columns ----
__global__ void k_gather_wo(const int* __restrict__ idx, const float* __restrict__ Wo,
                            u16* __restrict__ WoSel) {
  __shared__ int il[KS];
  int b = blockIdx.y, t = threadIdx.x;
  for (int k = t; k < KS; k += 256) il[k] = idx[b * KS + k];
  __syncthreads();
  int o0 = blockIdx.x * 8;
  for (int oo = 0; oo < 8; ++oo) {
    int o = o0 + oo;
    const float* wr = Wo + (size_t)o * NC;
    u16* dst = WoSel + ((size_t)b * NC + o) * KS;
    for (int k = t; k < KS; k += 256) dst[k] = f2bf(wr[il[k]]);
  }
}

// ---- merge 2 Gram split-K partials (packed lower tiles) -> full symmetric bf16 G ----
__global__ void k_gmerge(const float* __restrict__ Gp, u16* __restrict__ G) {
  __shared__ u16 gl[128][130];
  int tt = blockIdx.x, b = blockIdx.y, t = threadIdx.x;
  int i = 0;
  while ((i + 1) * (i + 2) / 2 <= tt) ++i;
  int j = tt - i * (i + 1) / 2;
  const float* p0 = Gp + ((size_t)(0 * NB + b) * 21 + tt) * 16384;
  const float* p1 = Gp + ((size_t)(1 * NB + b) * 21 + tt) * 16384;
#pragma unroll
  for (int s = 0; s < 16; ++s) {
    int id = t + 256 * s;
    int row = id >> 5, col4 = (id & 31) * 4;
    float4 a = *(const float4*)&p0[row * 128 + col4];
    float4 bb = *(const float4*)&p1[row * 128 + col4];
    usv4 pk = {f2bf(a.x + bb.x), f2bf(a.y + bb.y), f2bf(a.z + bb.z), f2bf(a.w + bb.w)};
    gl[row][col4] = pk[0]; gl[row][col4 + 1] = pk[1];
    gl[row][col4 + 2] = pk[2]; gl[row][col4 + 3] = pk[3];
    *(usv4*)&G[((size_t)b * NC + i * 128 + row) * NC + j * 128 + col4] = pk;
  }
  if (i == j) return;
  __syncthreads();
#pragma unroll
  for (int s = 0; s < 16; ++s) {
    int id = t + 256 * s;
    int row = id >> 5, col4 = (id & 31) * 4;
    usv4 pk = {gl[col4][row], gl[col4 + 1][row], gl[col4 + 2][row], gl[col4 + 3][row]};
    *(usv4*)&G[((size_t)b * NC + j * 128 + row) * NC + i * 128 + col4] = pk;
  }
}

// ---- row softmax of S, write transposed bf16 At[b][l][k] ----
__global__ void k_softmax(const float* __restrict__ S, u16* __restrict__ At) {
  __shared__ float sh[2];
  int kk = blockIdx.x, b = blockIdx.y, t = threadIdx.x;  // 128 threads
  const float* srow = S + ((size_t)b * KS + kk) * KS;
  float v[3];
#pragma unroll
  for (int i = 0; i < 3; ++i) v[i] = srow[t + 128 * i];
  float m = fmaxf(fmaxf(v[0], v[1]), v[2]);
#pragma unroll
  for (int s = 32; s; s >>= 1) m = fmaxf(m, __shfl_xor(m, s));
  if ((t & 63) == 0) sh[t >> 6] = m;
  __syncthreads();
  m = fmaxf(sh[0], sh[1]);
  float e[3];
  float sum = 0.f;
#pragma unroll
  for (int i = 0; i < 3; ++i) { e[i] = expf(v[i] - m); sum += e[i]; }
#pragma unroll
  for (int s = 32; s; s >>= 1) sum += __shfl_xor(sum, s);
  __syncthreads();
  if ((t & 63) == 0) sh[t >> 6] = sum;
  __syncthreads();
  sum = sh[0] + sh[1];
  float inv = 1.f / sum;
#pragma unroll
  for (int i = 0; i < 3; ++i) {
    int l = t + 128 * i;
    At[((size_t)b * KS + l) * KS + kk] = f2bf(e[i] * inv);
  }
}

// ---- bias_fin[b][o] = bo[o] + sum_l R[b][o][l] * betav[b][l] ----
__global__ void k_bias_fin(const u16* __restrict__ R, const float* __restrict__ biasq,
                           const float* __restrict__ bo, float* __restrict__ bias_fin) {
  __shared__ float bvl[KS];
  int b = blockIdx.y, t = threadIdx.x, lane = t & 63, w = t >> 6;
  for (int l = t; l < KS; l += 256) bvl[l] = biasq[b * 1152 + 768 + l];
  __syncthreads();
  int o0 = blockIdx.x * 16;
  for (int oo = w; oo < 16; oo += 4) {
    int o = o0 + oo;
    const u16* rr = R + ((size_t)b * NC + o) * KS;
    float acc = 0.f;
#pragma unroll
    for (int e = 0; e < 6; ++e) {
      int l = lane + 64 * e;
      acc += bf2f(rr[l]) * bvl[l];
    }
#pragma unroll
    for (int m = 32; m; m >>= 1) acc += __shfl_xor(acc, m);
    if (lane == 0) bias_fin[b * NC + o] = acc + bo[o];
  }
}

// ---- GEMM C = A @ Bt^T: global_load_lds staging, XOR-swizzled LDS,
//      prefetch double-buffer (issue tile t+1 loads BEFORE computing tile t;
//      one barrier/tile -> the vmcnt(0) drain lands after ~300cy of compute) ----
// EPI 1: S fp32 + rank-1 bias corrections, *scale
// EPI 2: bf16 C[b][row][col]
// EPI 3: fp32 C + bias[b][row]; 1D grid (3072), XCD-chunked y-fastest decode
// EPI 5: Gram partial, packed lower-tri tiles, split-K=2; 1D grid (672), XCD-chunked
template <int EPI>
__global__ __launch_bounds__(256, 2) void gemm_bt(
    const u16* __restrict__ A, const u16* __restrict__ Bt, size_t sA, size_t sB,
    int ldA, int ldB, int K, const float* __restrict__ bias, int bstride,
    float* __restrict__ outF, u16* __restrict__ outU, int ldC, size_t sC,
    const float* __restrict__ sigp, const float* __restrict__ bqp, float scale) {
  __shared__ u16 As0[128 * BK], As1[128 * BK];
  __shared__ u16 Bs0[128 * BK], Bs1[128 * BK];
  int b, m0 = 0, n0 = 0, kbeg = 0, kend = K, tt = 0, gpart = 0;
  if constexpr (EPI == 5) {
    int f = blockIdx.x;
    int w = (f & 7) * 84 + (f >> 3);
    int z = w / 21; tt = w - z * 21;
    b = z >> 1; gpart = z & 1;
    int ii = 0;
    while ((ii + 1) * (ii + 2) / 2 <= tt) ++ii;
    int jj = tt - ii * (ii + 1) / 2;
    m0 = ii * 128; n0 = jj * 128;
    kbeg = gpart * 2048; kend = kbeg + 2048;
  } else if constexpr (EPI == 3) {
    int f = blockIdx.x;
    int w = (f & 7) * 384 + (f >> 3);
    b = w / 192; int r = w - b * 192;
    int xx = r / 6, yy = r - xx * 6;
    m0 = yy * 128; n0 = xx * 128;
  } else {
    b = blockIdx.z; m0 = blockIdx.y * 128; n0 = blockIdx.x * 128;
  }
  const u16* Ab = A + (size_t)b * sA;
  const u16* Bb = Bt + (size_t)b * sB;
  int t = threadIdx.x, lane = t & 63, w = t >> 6;
  int wm = (w >> 1) * 64, wn = (w & 1) * 64;
  int r16 = lane & 15, g = lane >> 4;

  int srow = w * 32 + (lane >> 3);
  // pre-swizzled source column: LDS slot (lane&7) of row gets logical granule (lane&7)^(lane>>3)
  int scol = (((lane & 7) ^ (lane >> 3)) & 7) * 8;
  const u16* Ag = Ab + (size_t)(m0 + srow) * ldA + kbeg + scol;
  const u16* Bg = Bb + (size_t)(n0 + srow) * ldB + kbeg + scol;
  int wlds = (w * 32) * BK;

  fx4 acc[4][4] = {};

  auto stage = [&](u16* Asl, u16* Bsl) {
#pragma unroll
    for (int s = 0; s < 4; ++s) gload16(Ag + (size_t)s * 8 * ldA, Asl + wlds + s * 8 * BK);
#pragma unroll
    for (int s = 0; s < 4; ++s) gload16(Bg + (size_t)s * 8 * ldB, Bsl + wlds + s * 8 * BK);
    Ag += BK; Bg += BK;
  };
  auto compute = [&](const u16* As_, const u16* Bs_) {
#pragma unroll
    for (int kk = 0; kk < 2; ++kk) {
      bfx8 af[4], bfr[4];
      int swz = ((kk * 4 + g) ^ (r16 & 7)) * 8;  // swizzled read granule
#pragma unroll
      for (int i = 0; i < 4; ++i) {
        af[i] = *(const bfx8*)&As_[(wm + i * 16 + r16) * BK + swz];
        bfr[i] = *(const bfx8*)&Bs_[(wn + i * 16 + r16) * BK + swz];
      }
#pragma unroll
      for (int i = 0; i < 4; ++i)
#pragma unroll
        for (int j = 0; j < 4; ++j)
          acc[i][j] = __builtin_amdgcn_mfma_f32_16x16x32_bf16(af[i], bfr[j], acc[i][j], 0, 0, 0);
    }
  };

  // nt = (kend-kbeg)/BK is always even here (6, 12, or 32)
  int nt = (kend - kbeg) >> 6;
  stage(As0, Bs0);          // tile 0
  __syncthreads();
  for (int it = 0; it < nt; it += 2) {
    stage(As1, Bs1);        // tile it+1 (always exists: nt even)
    compute(As0, Bs0);      // tile it
    __syncthreads();        // drains prefetch (hidden under compute) + ds_reads
    if (it + 2 < nt) stage(As0, Bs0);  // tile it+2
    compute(As1, Bs1);      // tile it+1
    __syncthreads();
  }

#pragma unroll
  for (int i = 0; i < 4; ++i) {
#pragma unroll
    for (int j = 0; j < 4; ++j) {
      int row = wm + i * 16 + g * 4;   // tile-local
      int col = wn + j * 16 + r16;     // tile-local
      fx4 v = acc[i][j];
      if constexpr (EPI == 1) {        // S with exact bias corrections
        int gc = n0 + col;
        float bk_ = bqp[b * 1152 + 384 + gc];
        float sk_ = sigp[b * NC + 384 + gc];
#pragma unroll
        for (int r = 0; r < 4; ++r) {
          int gr = m0 + row + r;
          float bq_ = bqp[b * 1152 + gr];
          float sq_ = sigp[b * NC + gr];
          float val = (v[r] + bq_ * sk_ + bk_ * sq_ + 4096.f * bq_ * bk_) * scale;
          outF[(size_t)b * sC + (size_t)gr * ldC + gc] = val;
        }
      } else if constexpr (EPI == 2) { // bf16 C
#pragma unroll
        for (int r = 0; r < 4; ++r)
          outU[(size_t)b * sC + (size_t)(m0 + row + r) * ldC + (n0 + col)] = f2bf(v[r]);
      } else if constexpr (EPI == 3) { // fp32 + per-batch bias
#pragma unroll
        for (int r = 0; r < 4; ++r)
          outF[(size_t)b * sC + (size_t)(m0 + row + r) * ldC + (n0 + col)] =
              v[r] + bias[b * bstride + m0 + row + r];
      } else {                         // EPI 5: Gram partial, packed tile
        float* o = outF + ((size_t)(gpart * NB + b) * 21 + tt) * 16384;
#pragma unroll
        for (int r = 0; r < 4; ++r) o[(row + r) * 128 + col] = v[r];
      }
    }
  }
}

__global__ void k_sentinel(float* out, int n) {
  int id = blockIdx.x * 256 + threadIdx.x;
  if (id < n) out[id] = 12345.0f;
}

extern "C" void kernel_launch(void* const* d_in, const int* in_sizes, int n_in,
                              void* d_out, int out_size, void* d_ws, size_t ws_size,
                              hipStream_t stream) {
  const float* x    = (const float*)d_in[0];
  const float* temb = (const float*)d_in[1];
  const float* W_ts = (const float*)d_in[2];
  const float* b_ts = (const float*)d_in[3];
  const float* W_tp = (const float*)d_in[4];
  const float* b_tp = (const float*)d_in[5];
  const float* W_m1 = (const float*)d_in[6];
  const float* b_m1 = (const float*)d_in[7];
  const float* W_m2 = (const float*)d_in[8];
  const float* b_m2 = (const float*)d_in[9];
  const float* Wq = (const float*)d_in[10];
  const float* bq = (const float*)d_in[11];
  const float* Wk = (const float*)d_in[12];
  const float* bk = (const float*)d_in[13];
  const float* Wv = (const float*)d_in[14];
  const float* bv = (const float*)d_in[15];
  const float* Wo = (const float*)d_in[16];
  const float* bo = (const float*)d_in[17];
  float* out = (float*)d_out;

  char* base = (char*)d_ws;
  size_t off = 0;
  auto alloc = [&](size_t bytes) -> char* {
    char* pp = base + off;
    off += (bytes + 255) & ~(size_t)255;
    return pp;
  };
  u16* xT   = (u16*)alloc((size_t)NB * NPX * NC * 2);    // 100.7 MB, live to end
  u16* xC   = (u16*)alloc((size_t)NB * NC * NPX * 2);    // 100.7 MB; G/T/S/At/R/W_eff overlay after G-gemm
  u16* Aq   = (u16*)alloc((size_t)NB * 768 * NC * 2);    // 18.9 MB (q,k rows)
  u16* AvT  = (u16*)alloc((size_t)NB * NC * KS * 2);     // 9.4 MB
  u16* WoS  = (u16*)alloc((size_t)NB * NC * KS * 2);     // 9.4 MB
  float* Gp = (float*)alloc((size_t)2 * NB * 21 * 16384 * 4);  // 44.0 MB; hosts Avtmp early
  float* parts  = (float*)alloc((size_t)NB * NC * 64 * 4);
  float* xmean  = (float*)alloc((size_t)NB * NC * 4);
  float* Y1     = (float*)alloc((size_t)NB * 2304 * 4);
  float* st     = (float*)alloc((size_t)NB * NT * 4);
  float* p      = (float*)alloc((size_t)NB * 1536 * 4);
  float* hid    = (float*)alloc((size_t)NB * 1536 * 4);
  float* pr     = (float*)alloc((size_t)NB * NC * 4);
  int*   idx    = (int*)alloc((size_t)NB * KS * 4);
  float* biasq  = (float*)alloc((size_t)NB * 1152 * 4);
  float* sig    = (float*)alloc((size_t)NB * NC * 4);
  float* bias_fin = (float*)alloc((size_t)NB * NC * 4);

  if (off > ws_size) {
    k_sentinel<<<(out_size + 255) / 256, 256, 0, stream>>>(out, out_size);
    return;
  }

  // overlays
  u16* Avtmp = (u16*)Gp;                                // 9.4 MB, fold -> avt, dead before G-gemm
  u16* G   = (u16*)xC;                                  // 18.9 MB, after G-gemm frees xC
  u16* T   = (u16*)((char*)xC + 20u * 1024 * 1024);     // 9.4 MB
  float* S = (float*)((char*)xC + 32u * 1024 * 1024);   // 9.4 MB
  u16* At  = (u16*)((char*)xC + 44u * 1024 * 1024);     // 4.7 MB
  u16* R   = (u16*)((char*)xC + 52u * 1024 * 1024);     // 9.4 MB
  u16* Wf  = (u16*)((char*)xC + 64u * 1024 * 1024);     // 18.9 MB

  k_trans_mean<<<dim3(64, 12, NB), 256, 0, stream>>>(x, xT, xC, parts);
  k_misc<<<48, 256, 0, stream>>>(parts, xmean, temb, st);
  k_mlp8<<<dim3(96, 2), 256, 0, stream>>>(W_ts, b_ts, st, Y1, 512, 1536, 2304, 0, 0);
  k_mlp8<<<dim3(48, 2), 256, 0, stream>>>(W_tp, b_tp, st, Y1, 512, 768, 2304, 1536, 0);
  k_assemble_p<<<(NB * NC + 255) / 256, 256, 0, stream>>>(Y1, xmean, p);
  k_mlp8<<<dim3(96, 2), 256, 0, stream>>>(W_m1, b_m1, p, hid, 1536, 1536, 1536, 0, 1);
  k_mlp8<<<dim3(48, 2), 256, 0, stream>>>(W_m2, b_m2, hid, pr, 1536, 768, 768, 0, 0);
  k_topk<<<NB, 256, 0, stream>>>(pr, idx);
  k_fold<<<dim3(KS, NB), 256, 0, stream>>>(idx, Y1, xmean, Wq, bq, Wk, bk, Wv, bv,
                                           Aq, Avtmp, biasq, sig);
  k_avt<<<dim3(72, NB), 256, 0, stream>>>(Avtmp, AvT);
  k_gather_wo<<<dim3(96, NB), 256, 0, stream>>>(idx, Wo, WoS);

  // G = xC @ xC^T (symmetric, lower tiles, split-K=2, packed fp32 partials), XCD-swizzled
  gemm_bt<5><<<672, 256, 0, stream>>>(
      xC, xC, (size_t)NC * NPX, (size_t)NC * NPX, NPX, NPX, NPX,
      nullptr, 0, Gp, nullptr, 0, 0, nullptr, nullptr, 0.f);
  k_gmerge<<<dim3(21, NB), 256, 0, stream>>>(Gp, G);
  // T = Ak @ G -> bf16 [b][384][768]
  gemm_bt<2><<<dim3(6, 3, NB), 256, 0, stream>>>(
      Aq + (size_t)KS * NC, G, (size_t)768 * NC, (size_t)NC * NC, NC, NC, NC,
      nullptr, 0, nullptr, T, NC, (size_t)KS * NC, nullptr, nullptr, 0.f);
  // S = (Aq @ T^T + rank-1 bias corrections) * scale -> fp32 [b][384][384]
  gemm_bt<1><<<dim3(3, 3, NB), 256, 0, stream>>>(
      Aq, T, (size_t)768 * NC, (size_t)KS * NC, NC, NC, NC,
      nullptr, 0, S, nullptr, KS, (size_t)KS * KS, sig, biasq, 0.05103103630798287f);
  k_softmax<<<dim3(KS, NB), 128, 0, stream>>>(S, At);
  // R = WoS @ attn (Bt = At = attn^T) -> bf16 [b][768][384]
  gemm_bt<2><<<dim3(3, 6, NB), 256, 0, stream>>>(
      WoS, At, (size_t)NC * KS, (size_t)KS * KS, KS, KS, KS,
      nullptr, 0, nullptr, R, KS, (size_t)NC * KS, nullptr, nullptr, 0.f);
  k_bias_fin<<<dim3(48, NB), 256, 0, stream>>>(R, biasq, bo, bias_fin);
  // W_eff = R @ AvT^T -> bf16 [b][768][768]
  gemm_bt<2><<<dim3(6, 6, NB), 256, 0, stream>>>(
      R, AvT, (size_t)NC * KS, (size_t)NC * KS, KS, KS, KS,
      nullptr, 0, nullptr, Wf, NC, (size_t)NC * NC, nullptr, nullptr, 0.f);
  // out = W_eff @ xT^T + bias_fin -> fp32 [b][768][4096], XCD-swizzled
  gemm_bt<3><<<3072, 256, 0, stream>>>(
      Wf, xT, (size_t)NC * NC, (size_t)NPX * NC, NC, NC, NC,
      bias_fin, NC, out, nullptr, NPX, (size_t)NC * NPX, nullptr, nullptr, 0.f);
}

// Round 10
// 651.280 us; speedup vs baseline: 1.3809x; 1.0050x over previous
//
#include <hip/hip_runtime.h>

#define NB 16
#define NC 768
#define NT 512
#define KS 384
#define NPX 4096
#define BK 64

typedef __bf16 bfx8 __attribute__((ext_vector_type(8)));
typedef float fx4 __attribute__((ext_vector_type(4)));
typedef unsigned short u16;
typedef unsigned short usv4 __attribute__((ext_vector_type(4)));

__device__ __forceinline__ u16 f2bf(float f) {
  unsigned u = __builtin_bit_cast(unsigned, f);
  u += 0x7FFFu + ((u >> 16) & 1u);
  return (u16)(u >> 16);
}
__device__ __forceinline__ float bf2f(u16 v) {
  return __builtin_bit_cast(float, (unsigned)v << 16);
}

__device__ __forceinline__ void gload16(const u16* g, u16* l) {
  __builtin_amdgcn_global_load_lds(
      (const __attribute__((address_space(1))) unsigned int*)g,
      (__attribute__((address_space(3))) unsigned int*)l, 16, 0, 0);
}

// ---- K1: x -> bf16 xT[b][px][c] (transposed) + xC[b][c][px] (cast) + partial sums ----
__global__ void k_trans_mean(const float* __restrict__ x, u16* __restrict__ xT,
                             u16* __restrict__ xC, float* __restrict__ parts) {
  __shared__ float ld[64][65];
  int p0 = blockIdx.x * 64, c0 = blockIdx.y * 64, b = blockIdx.z;
  int t = threadIdx.x;
  int k = t & 15, ir = t >> 4;
  int jr = k * 4;
#pragma unroll
  for (int s = 0; s < 4; ++s) {
    int i = ir + s * 16;
    float4 v = *(const float4*)&x[(size_t)(b * NC + c0 + i) * NPX + p0 + jr];
    ld[i][jr] = v.x; ld[i][jr + 1] = v.y; ld[i][jr + 2] = v.z; ld[i][jr + 3] = v.w;
    usv4 pk = {f2bf(v.x), f2bf(v.y), f2bf(v.z), f2bf(v.w)};
    *(usv4*)&xC[(size_t)(b * NC + c0 + i) * NPX + p0 + jr] = pk;
  }
  __syncthreads();
#pragma unroll
  for (int s = 0; s < 4; ++s) {
    int j = ir + s * 16;
    usv4 pk = {f2bf(ld[k * 4][j]), f2bf(ld[k * 4 + 1][j]),
               f2bf(ld[k * 4 + 2][j]), f2bf(ld[k * 4 + 3][j])};
    *(usv4*)&xT[(size_t)(b * NPX + p0 + j) * NC + c0 + k * 4] = pk;
  }
  if (t < 64) {
    float s = 0.f;
    for (int j = 0; j < 64; ++j) s += ld[t][j];
    parts[(size_t)(b * NC + c0 + t) * 64 + blockIdx.x] = s;
  }
}

// ---- fused: xmean finalize + silu(temb) ----
__global__ void k_misc(const float* __restrict__ parts, float* __restrict__ xmean,
                       const float* __restrict__ temb, float* __restrict__ st) {
  int id = blockIdx.x * 256 + threadIdx.x;
  if (id < NB * NT) { float v = temb[id]; st[id] = v / (1.f + expf(-v)); }
  if (id < NB * NC) {
    float s = 0.f;
    for (int j = 0; j < 64; ++j) s += parts[(size_t)id * 64 + j];
    xmean[id] = s * (1.f / 4096.f);
  }
}

// ---- small batched MLP: wide launch, weights spread across blocks ----
__global__ void k_mlp8(const float* __restrict__ W, const float* __restrict__ bias,
                       const float* __restrict__ X, float* __restrict__ Y,
                       int len, int nj, int ostride, int obase, int dosilu) {
  __shared__ float Xs[8 * 1537];
  int t = threadIdx.x, lane = t & 63, w = t >> 6;
  int b0 = blockIdx.y * 8;
  int ldx = len + 1;
  for (int id = t; id < 8 * len; id += 256) {
    int bb = id / len, s = id - bb * len;
    Xs[bb * ldx + s] = X[(size_t)(b0 + bb) * len + s];
  }
  __syncthreads();
  for (int i = 0; i < 4; ++i) {
    int j = blockIdx.x * 16 + i * 4 + w;
    if (j < nj) {
      float acc[8] = {0, 0, 0, 0, 0, 0, 0, 0};
      for (int s = lane; s < len; s += 64) {
        float wv = W[(size_t)j * len + s];
#pragma unroll
        for (int bb = 0; bb < 8; ++bb) acc[bb] += wv * Xs[bb * ldx + s];
      }
#pragma unroll
      for (int bb = 0; bb < 8; ++bb) {
        float r = acc[bb];
#pragma unroll
        for (int m = 32; m; m >>= 1) r += __shfl_xor(r, m);
        if (lane == 0) {
          r += bias[j];
          if (dosilu) r = r / (1.f + expf(-r));
          Y[(size_t)(b0 + bb) * ostride + obase + j] = r;
        }
      }
    }
  }
}

// ---- p = [gap, tp]; gap = xmean*(1+scale)+shift ----
__global__ void k_assemble_p(const float* __restrict__ Y1, const float* __restrict__ xmean,
                             float* __restrict__ p) {
  int id = blockIdx.x * 256 + threadIdx.x;
  if (id >= NB * NC) return;
  int b = id / NC, c = id - b * NC;
  const float* yb = Y1 + (size_t)b * 2304;
  p[(size_t)b * 1536 + c] = xmean[id] * (1.f + yb[c]) + yb[768 + c];
  p[(size_t)b * 1536 + 768 + c] = yb[1536 + c];
}

// ---- top-k by rank counting ----
__global__ void k_topk(const float* __restrict__ prompt, int* __restrict__ idx) {
  __shared__ float pr[NC];
  int b = blockIdx.x, t = threadIdx.x;
  for (int c = t; c < NC; c += 256) pr[c] = prompt[(size_t)b * NC + c];
  __syncthreads();
  for (int c = t; c < NC; c += 256) {
    float v = pr[c];
    int r = 0;
    for (int c2 = 0; c2 < NC; ++c2) {
      float v2 = pr[c2];
      r += (v2 > v) || (v2 == v && c2 < c);
    }
    if (r < KS) idx[b * KS + r] = c;
  }
}

// ---- fold scale into gathered rows; shift into bias; sigma for S corrections ----
__global__ void k_fold(const int* __restrict__ idx, const float* __restrict__ Y1,
                       const float* __restrict__ xmean,
                       const float* __restrict__ Wq, const float* __restrict__ bq,
                       const float* __restrict__ Wk, const float* __restrict__ bk,
                       const float* __restrict__ Wv, const float* __restrict__ bv,
                       u16* __restrict__ Aq, u16* __restrict__ Avtmp,
                       float* __restrict__ biasq, float* __restrict__ sig) {
  __shared__ float red[5 * 256];
  int k = blockIdx.x, b = blockIdx.y, t = threadIdx.x;
  int row = idx[b * KS + k];
  const float* yb = Y1 + (size_t)b * 2304;
  u16* aq = Aq + (size_t)b * 768 * NC;
  u16* av = Avtmp + (size_t)b * KS * NC;
  float dq = 0.f, dk = 0.f, dv = 0.f, sq = 0.f, sk = 0.f;
  for (int c = t; c < NC; c += 256) {
    float sc = 1.f + yb[c], sh = yb[768 + c];
    float xm = xmean[b * NC + c];
    float wq = Wq[(size_t)row * NC + c];
    float wk = Wk[(size_t)row * NC + c];
    float wv = Wv[(size_t)row * NC + c];
    aq[(size_t)k * NC + c] = f2bf(wq * sc);
    aq[(size_t)(KS + k) * NC + c] = f2bf(wk * sc);
    av[(size_t)k * NC + c] = f2bf(wv * sc);
    dq += wq * sh; dk += wk * sh; dv += wv * sh;
    sq += wq * sc * xm; sk += wk * sc * xm;
  }
  red[t] = dq; red[256 + t] = dk; red[512 + t] = dv; red[768 + t] = sq; red[1024 + t] = sk;
  __syncthreads();
  for (int s = 128; s; s >>= 1) {
    if (t < s) {
#pragma unroll
      for (int q = 0; q < 5; ++q) red[q * 256 + t] += red[q * 256 + t + s];
    }
    __syncthreads();
  }
  if (t == 0) {
    biasq[b * 1152 + k] = bq[row] + red[0];
    biasq[b * 1152 + KS + k] = bk[row] + red[256];
    biasq[b * 1152 + 2 * KS + k] = bv[row] + red[512];
    sig[b * NC + k] = 4096.f * red[768];
    sig[b * NC + KS + k] = 4096.f * red[1024];
  }
}

// ---- transpose Avtmp[b][384][768] -> AvT[b][768][384] ----
__global__ void k_avt(const u16* __restrict__ Avtmp, u16* __restrict__ AvT) {
  __shared__ u16 tl[64][65];
  int lt = blockIdx.x % 6, ct = blockIdx.x / 6, b = blockIdx.y;
  int l0 = lt * 64, c0 = ct * 64, t = threadIdx.x;
#pragma unroll
  for (int s = 0; s < 16; ++s) {
    int id = t + 256 * s;
    int r = id >> 6, c = id & 63;
    tl[r][c] = Avtmp[(size_t)b * KS * NC + (size_t)(l0 + r) * NC + c0 + c];
  }
  __syncthreads();
#pragma unroll
  for (int s = 0; s < 16; ++s) {
    int id = t + 256 * s;
    int r = id >> 6, c = id & 63;
    AvT[(size_t)b * NC * KS + (size_t)(c0 + r) * KS + l0 + c] = tl[c][r];
  }
}

// ---- gather Wo columns ----
__global__ void k_gather_wo(const int* __restrict__ idx, const float* __restrict__ Wo,
                            u16* __restrict__ WoSel) {
  __shared__ int il[KS];
  int b = blockIdx.y, t = threadIdx.x;
  for (int k = t; k < KS; k += 256) il[k] = idx[b * KS + k];
  __syncthreads();
  int o0 = blockIdx.x * 8;
  for (int oo = 0; oo < 8; ++oo) {
    int o = o0 + oo;
    const float* wr = Wo + (size_t)o * NC;
    u16* dst = WoSel + ((size_t)b * NC + o) * KS;
    for (int k = t; k < KS; k += 256) dst[k] = f2bf(wr[il[k]]);
  }
}

// ---- merge 2 Gram split-K partials (packed lower tiles) -> full symmetric bf16 G ----
__global__ void k_gmerge(const float* __restrict__ Gp, u16* __restrict__ G) {
  __shared__ u16 gl[128][130];
  int tt = blockIdx.x, b = blockIdx.y, t = threadIdx.x;
  int i = 0;
  while ((i + 1) * (i + 2) / 2 <= tt) ++i;
  int j = tt - i * (i + 1) / 2;
  const float* p0 = Gp + ((size_t)(0 * NB + b) * 21 + tt) * 16384;
  const float* p1 = Gp + ((size_t)(1 * NB + b) * 21 + tt) * 16384;
#pragma unroll
  for (int s = 0; s < 16; ++s) {
    int id = t + 256 * s;
    int row = id >> 5, col4 = (id & 31) * 4;
    float4 a = *(const float4*)&p0[row * 128 + col4];
    float4 bb = *(const float4*)&p1[row * 128 + col4];
    usv4 pk = {f2bf(a.x + bb.x), f2bf(a.y + bb.y), f2bf(a.z + bb.z), f2bf(a.w + bb.w)};
    gl[row][col4] = pk[0]; gl[row][col4 + 1] = pk[1];
    gl[row][col4 + 2] = pk[2]; gl[row][col4 + 3] = pk[3];
    *(usv4*)&G[((size_t)b * NC + i * 128 + row) * NC + j * 128 + col4] = pk;
  }
  if (i == j) return;
  __syncthreads();
#pragma unroll
  for (int s = 0; s < 16; ++s) {
    int id = t + 256 * s;
    int row = id >> 5, col4 = (id & 31) * 4;
    usv4 pk = {gl[col4][row], gl[col4 + 1][row], gl[col4 + 2][row], gl[col4 + 3][row]};
    *(usv4*)&G[((size_t)b * NC + j * 128 + row) * NC + i * 128 + col4] = pk;
  }
}

// ---- row softmax of S, write transposed bf16 At[b][l][k] ----
__global__ void k_softmax(const float* __restrict__ S, u16* __restrict__ At) {
  __shared__ float sh[2];
  int kk = blockIdx.x, b = blockIdx.y, t = threadIdx.x;  // 128 threads
  const float* srow = S + ((size_t)b * KS + kk) * KS;
  float v[3];
#pragma unroll
  for (int i = 0; i < 3; ++i) v[i] = srow[t + 128 * i];
  float m = fmaxf(fmaxf(v[0], v[1]), v[2]);
#pragma unroll
  for (int s = 32; s; s >>= 1) m = fmaxf(m, __shfl_xor(m, s));
  if ((t & 63) == 0) sh[t >> 6] = m;
  __syncthreads();
  m = fmaxf(sh[0], sh[1]);
  float e[3];
  float sum = 0.f;
#pragma unroll
  for (int i = 0; i < 3; ++i) { e[i] = expf(v[i] - m); sum += e[i]; }
#pragma unroll
  for (int s = 32; s; s >>= 1) sum += __shfl_xor(sum, s);
  __syncthreads();
  if ((t & 63) == 0) sh[t >> 6] = sum;
  __syncthreads();
  sum = sh[0] + sh[1];
  float inv = 1.f / sum;
#pragma unroll
  for (int i = 0; i < 3; ++i) {
    int l = t + 128 * i;
    At[((size_t)b * KS + l) * KS + kk] = f2bf(e[i] * inv);
  }
}

// ---- bias_fin[b][o] = bo[o] + sum_l R[b][o][l] * betav[b][l] ----
__global__ void k_bias_fin(const u16* __restrict__ R, const float* __restrict__ biasq,
                           const float* __restrict__ bo, float* __restrict__ bias_fin) {
  __shared__ float bvl[KS];
  int b = blockIdx.y, t = threadIdx.x, lane = t & 63, w = t >> 6;
  for (int l = t; l < KS; l += 256) bvl[l] = biasq[b * 1152 + 768 + l];
  __syncthreads();
  int o0 = blockIdx.x * 16;
  for (int oo = w; oo < 16; oo += 4) {
    int o = o0 + oo;
    const u16* rr = R + ((size_t)b * NC + o) * KS;
    float acc = 0.f;
#pragma unroll
    for (int e = 0; e < 6; ++e) {
      int l = lane + 64 * e;
      acc += bf2f(rr[l]) * bvl[l];
    }
#pragma unroll
    for (int m = 32; m; m >>= 1) acc += __shfl_xor(acc, m);
    if (lane == 0) bias_fin[b * NC + o] = acc + bo[o];
  }
}

// ---- GEMM C = A @ Bt^T: global_load_lds staging, XOR-swizzled LDS,
//      2-deep prefetch + COUNTED vmcnt barriers (T4): 16 loads in flight
//      entering each tile; vmcnt(8) retires exactly the tile being consumed;
//      drain-free s_barrier guards buffer overwrite. Never vmcnt(0) mid-loop. ----
// EPI 1: S fp32 + rank-1 bias corrections, *scale
// EPI 2: bf16 C[b][row][col]
// EPI 3: fp32 C + bias[b][row]; 1D grid (3072), XCD-chunked y-fastest decode
// EPI 5: Gram partial, packed lower-tri tiles, split-K=2; 1D grid (672), XCD-chunked
template <int EPI>
__global__ __launch_bounds__(256, 2) void gemm_bt(
    const u16* __restrict__ A, const u16* __restrict__ Bt, size_t sA, size_t sB,
    int ldA, int ldB, int K, const float* __restrict__ bias, int bstride,
    float* __restrict__ outF, u16* __restrict__ outU, int ldC, size_t sC,
    const float* __restrict__ sigp, const float* __restrict__ bqp, float scale) {
  __shared__ u16 As0[128 * BK], As1[128 * BK];
  __shared__ u16 Bs0[128 * BK], Bs1[128 * BK];
  int b, m0 = 0, n0 = 0, kbeg = 0, kend = K, tt = 0, gpart = 0;
  if constexpr (EPI == 5) {
    int f = blockIdx.x;
    int w = (f & 7) * 84 + (f >> 3);
    int z = w / 21; tt = w - z * 21;
    b = z >> 1; gpart = z & 1;
    int ii = 0;
    while ((ii + 1) * (ii + 2) / 2 <= tt) ++ii;
    int jj = tt - ii * (ii + 1) / 2;
    m0 = ii * 128; n0 = jj * 128;
    kbeg = gpart * 2048; kend = kbeg + 2048;
  } else if constexpr (EPI == 3) {
    int f = blockIdx.x;
    int w = (f & 7) * 384 + (f >> 3);
    b = w / 192; int r = w - b * 192;
    int xx = r / 6, yy = r - xx * 6;
    m0 = yy * 128; n0 = xx * 128;
  } else {
    b = blockIdx.z; m0 = blockIdx.y * 128; n0 = blockIdx.x * 128;
  }
  const u16* Ab = A + (size_t)b * sA;
  const u16* Bb = Bt + (size_t)b * sB;
  int t = threadIdx.x, lane = t & 63, w = t >> 6;
  int wm = (w >> 1) * 64, wn = (w & 1) * 64;
  int r16 = lane & 15, g = lane >> 4;

  int srow = w * 32 + (lane >> 3);
  // pre-swizzled source column: LDS slot (lane&7) of row gets logical granule (lane&7)^(lane>>3)
  int scol = (((lane & 7) ^ (lane >> 3)) & 7) * 8;
  const u16* Ag = Ab + (size_t)(m0 + srow) * ldA + kbeg + scol;
  const u16* Bg = Bb + (size_t)(n0 + srow) * ldB + kbeg + scol;
  int wlds = (w * 32) * BK;

  fx4 acc[4][4] = {};

  auto stage = [&](u16* Asl, u16* Bsl) {
#pragma unroll
    for (int s = 0; s < 4; ++s) gload16(Ag + (size_t)s * 8 * ldA, Asl + wlds + s * 8 * BK);
#pragma unroll
    for (int s = 0; s < 4; ++s) gload16(Bg + (size_t)s * 8 * ldB, Bsl + wlds + s * 8 * BK);
    Ag += BK; Bg += BK;
  };
  auto compute = [&](const u16* As_, const u16* Bs_) {
#pragma unroll
    for (int kk = 0; kk < 2; ++kk) {
      bfx8 af[4], bfr[4];
      int swz = ((kk * 4 + g) ^ (r16 & 7)) * 8;  // swizzled read granule
#pragma unroll
      for (int i = 0; i < 4; ++i) {
        af[i] = *(const bfx8*)&As_[(wm + i * 16 + r16) * BK + swz];
        bfr[i] = *(const bfx8*)&Bs_[(wn + i * 16 + r16) * BK + swz];
      }
#pragma unroll
      for (int i = 0; i < 4; ++i)
#pragma unroll
        for (int j = 0; j < 4; ++j)
          acc[i][j] = __builtin_amdgcn_mfma_f32_16x16x32_bf16(af[i], bfr[j], acc[i][j], 0, 0, 0);
    }
  };

  // nt even (6, 12, or 32). 2-deep prefetch; invariant: 16 loads outstanding
  // entering each tile; vmcnt(8) retires the consumed tile's 8.
  int nt = (kend - kbeg) >> 6;
  stage(As0, Bs0);   // tile 0
  stage(As1, Bs1);   // tile 1
  for (int it = 0; it < nt; it += 2) {
    asm volatile("s_waitcnt vmcnt(8)\n\ts_barrier" ::: "memory");  // tile it ready
    compute(As0, Bs0);
    asm volatile("s_barrier" ::: "memory");                        // done reading buf0
    if (it + 2 < nt) {
      stage(As0, Bs0);                                             // tile it+2
      asm volatile("s_waitcnt vmcnt(8)\n\ts_barrier" ::: "memory");// tile it+1 ready
    } else {
      asm volatile("s_waitcnt vmcnt(0)\n\ts_barrier" ::: "memory");// last pair: drain
    }
    compute(As1, Bs1);
    asm volatile("s_barrier" ::: "memory");                        // done reading buf1
    if (it + 3 < nt) stage(As1, Bs1);                              // tile it+3
  }

#pragma unroll
  for (int i = 0; i < 4; ++i) {
#pragma unroll
    for (int j = 0; j < 4; ++j) {
      int row = wm + i * 16 + g * 4;   // tile-local
      int col = wn + j * 16 + r16;     // tile-local
      fx4 v = acc[i][j];
      if constexpr (EPI == 1) {        // S with exact bias corrections
        int gc = n0 + col;
        float bk_ = bqp[b * 1152 + 384 + gc];
        float sk_ = sigp[b * NC + 384 + gc];
#pragma unroll
        for (int r = 0; r < 4; ++r) {
          int gr = m0 + row + r;
          float bq_ = bqp[b * 1152 + gr];
          float sq_ = sigp[b * NC + gr];
          float val = (v[r] + bq_ * sk_ + bk_ * sq_ + 4096.f * bq_ * bk_) * scale;
          outF[(size_t)b * sC + (size_t)gr * ldC + gc] = val;
        }
      } else if constexpr (EPI == 2) { // bf16 C
#pragma unroll
        for (int r = 0; r < 4; ++r)
          outU[(size_t)b * sC + (size_t)(m0 + row + r) * ldC + (n0 + col)] = f2bf(v[r]);
      } else if constexpr (EPI == 3) { // fp32 + per-batch bias
#pragma unroll
        for (int r = 0; r < 4; ++r)
          outF[(size_t)b * sC + (size_t)(m0 + row + r) * ldC + (n0 + col)] =
              v[r] + bias[b * bstride + m0 + row + r];
      } else {                         // EPI 5: Gram partial, packed tile
        float* o = outF + ((size_t)(gpart * NB + b) * 21 + tt) * 16384;
#pragma unroll
        for (int r = 0; r < 4; ++r) o[(row + r) * 128 + col] = v[r];
      }
    }
  }
}

__global__ void k_sentinel(float* out, int n) {
  int id = blockIdx.x * 256 + threadIdx.x;
  if (id < n) out[id] = 12345.0f;
}

extern "C" void kernel_launch(void* const* d_in, const int* in_sizes, int n_in,
                              void* d_out, int out_size, void* d_ws, size_t ws_size,
                              hipStream_t stream) {
  const float* x    = (const float*)d_in[0];
  const float* temb = (const float*)d_in[1];
  const float* W_ts = (const float*)d_in[2];
  const float* b_ts = (const float*)d_in[3];
  const float* W_tp = (const float*)d_in[4];
  const float* b_tp = (const float*)d_in[5];
  const float* W_m1 = (const float*)d_in[6];
  const float* b_m1 = (const float*)d_in[7];
  const float* W_m2 = (const float*)d_in[8];
  const float* b_m2 = (const float*)d_in[9];
  const float* Wq = (const float*)d_in[10];
  const float* bq = (const float*)d_in[11];
  const float* Wk = (const float*)d_in[12];
  const float* bk = (const float*)d_in[13];
  const float* Wv = (const float*)d_in[14];
  const float* bv = (const float*)d_in[15];
  const float* Wo = (const float*)d_in[16];
  const float* bo = (const float*)d_in[17];
  float* out = (float*)d_out;

  char* base = (char*)d_ws;
  size_t off = 0;
  auto alloc = [&](size_t bytes) -> char* {
    char* pp = base + off;
    off += (bytes + 255) & ~(size_t)255;
    return pp;
  };
  u16* xT   = (u16*)alloc((size_t)NB * NPX * NC * 2);    // 100.7 MB, live to end
  u16* xC   = (u16*)alloc((size_t)NB * NC * NPX * 2);    // 100.7 MB; G/T/S/At/R/W_eff overlay after G-gemm
  u16* Aq   = (u16*)alloc((size_t)NB * 768 * NC * 2);    // 18.9 MB (q,k rows)
  u16* AvT  = (u16*)alloc((size_t)NB * NC * KS * 2);     // 9.4 MB
  u16* WoS  = (u16*)alloc((size_t)NB * NC * KS * 2);     // 9.4 MB
  float* Gp = (float*)alloc((size_t)2 * NB * 21 * 16384 * 4);  // 44.0 MB; hosts Avtmp early
  float* parts  = (float*)alloc((size_t)NB * NC * 64 * 4);
  float* xmean  = (float*)alloc((size_t)NB * NC * 4);
  float* Y1     = (float*)alloc((size_t)NB * 2304 * 4);
  float* st     = (float*)alloc((size_t)NB * NT * 4);
  float* p      = (float*)alloc((size_t)NB * 1536 * 4);
  float* hid    = (float*)alloc((size_t)NB * 1536 * 4);
  float* pr     = (float*)alloc((size_t)NB * NC * 4);
  int*   idx    = (int*)alloc((size_t)NB * KS * 4);
  float* biasq  = (float*)alloc((size_t)NB * 1152 * 4);
  float* sig    = (float*)alloc((size_t)NB * NC * 4);
  float* bias_fin = (float*)alloc((size_t)NB * NC * 4);

  if (off > ws_size) {
    k_sentinel<<<(out_size + 255) / 256, 256, 0, stream>>>(out, out_size);
    return;
  }

  // overlays
  u16* Avtmp = (u16*)Gp;                                // 9.4 MB, fold -> avt, dead before G-gemm
  u16* G   = (u16*)xC;                                  // 18.9 MB, after G-gemm frees xC
  u16* T   = (u16*)((char*)xC + 20u * 1024 * 1024);     // 9.4 MB
  float* S = (float*)((char*)xC + 32u * 1024 * 1024);   // 9.4 MB
  u16* At  = (u16*)((char*)xC + 44u * 1024 * 1024);     // 4.7 MB
  u16* R   = (u16*)((char*)xC + 52u * 1024 * 1024);     // 9.4 MB
  u16* Wf  = (u16*)((char*)xC + 64u * 1024 * 1024);     // 18.9 MB

  k_trans_mean<<<dim3(64, 12, NB), 256, 0, stream>>>(x, xT, xC, parts);
  k_misc<<<48, 256, 0, stream>>>(parts, xmean, temb, st);
  k_mlp8<<<dim3(96, 2), 256, 0, stream>>>(W_ts, b_ts, st, Y1, 512, 1536, 2304, 0, 0);
  k_mlp8<<<dim3(48, 2), 256, 0, stream>>>(W_tp, b_tp, st, Y1, 512, 768, 2304, 1536, 0);
  k_assemble_p<<<(NB * NC + 255) / 256, 256, 0, stream>>>(Y1, xmean, p);
  k_mlp8<<<dim3(96, 2), 256, 0, stream>>>(W_m1, b_m1, p, hid, 1536, 1536, 1536, 0, 1);
  k_mlp8<<<dim3(48, 2), 256, 0, stream>>>(W_m2, b_m2, hid, pr, 1536, 768, 768, 0, 0);
  k_topk<<<NB, 256, 0, stream>>>(pr, idx);
  k_fold<<<dim3(KS, NB), 256, 0, stream>>>(idx, Y1, xmean, Wq, bq, Wk, bk, Wv, bv,
                                           Aq, Avtmp, biasq, sig);
  k_avt<<<dim3(72, NB), 256, 0, stream>>>(Avtmp, AvT);
  k_gather_wo<<<dim3(96, NB), 256, 0, stream>>>(idx, Wo, WoS);

  // G = xC @ xC^T (symmetric, lower tiles, split-K=2, packed fp32 partials), XCD-swizzled
  gemm_bt<5><<<672, 256, 0, stream>>>(
      xC, xC, (size_t)NC * NPX, (size_t)NC * NPX, NPX, NPX, NPX,
      nullptr, 0, Gp, nullptr, 0, 0, nullptr, nullptr, 0.f);
  k_gmerge<<<dim3(21, NB), 256, 0, stream>>>(Gp, G);
  // T = Ak @ G -> bf16 [b][384][768]
  gemm_bt<2><<<dim3(6, 3, NB), 256, 0, stream>>>(
      Aq + (size_t)KS * NC, G, (size_t)768 * NC, (size_t)NC * NC, NC, NC, NC,
      nullptr, 0, nullptr, T, NC, (size_t)KS * NC, nullptr, nullptr, 0.f);
  // S = (Aq @ T^T + rank-1 bias corrections) * scale -> fp32 [b][384][384]
  gemm_bt<1><<<dim3(3, 3, NB), 256, 0, stream>>>(
      Aq, T, (size_t)768 * NC, (size_t)KS * NC, NC, NC, NC,
      nullptr, 0, S, nullptr, KS, (size_t)KS * KS, sig, biasq, 0.05103103630798287f);
  k_softmax<<<dim3(KS, NB), 128, 0, stream>>>(S, At);
  // R = WoS @ attn (Bt = At = attn^T) -> bf16 [b][768][384]
  gemm_bt<2><<<dim3(3, 6, NB), 256, 0, stream>>>(
      WoS, At, (size_t)NC * KS, (size_t)KS * KS, KS, KS, KS,
      nullptr, 0, nullptr, R, KS, (size_t)NC * KS, nullptr, nullptr, 0.f);
  k_bias_fin<<<dim3(48, NB), 256, 0, stream>>>(R, biasq, bo, bias_fin);
  // W_eff = R @ AvT^T -> bf16 [b][768][768]
  gemm_bt<2><<<dim3(6, 6, NB), 256, 0, stream>>>(
      R, AvT, (size_t)NC * KS, (size_t)NC * KS, KS, KS, KS,
      nullptr, 0, nullptr, Wf, NC, (size_t)NC * NC, nullptr, nullptr, 0.f);
  // out = W_eff @ xT^T + bias_fin -> fp32 [b][768][4096], XCD-swizzled
  gemm_bt<3><<<3072, 256, 0, stream>>>(
      Wf, xT, (size_t)NC * NC, (size_t)NPX * NC, NC, NC, NC,
      bias_fin, NC, out, nullptr, NPX, (size_t)NC * NPX, nullptr, nullptr, 0.f);
}